// Round 15
// baseline (814.287 us; speedup 1.0000x reference)
//
#include <hip/hip_runtime.h>
#include <hip/hip_bf16.h>

// SetTransformer encoder forward. B=32,N=2048,D=256,H=8,dh=32,NI=64,NL=3,NS=32.
// Round 15: attn_fused -> attn_split + attn_merge. Decomposition flipped from
// (b,head) to (b,key-range): block = 8 waves = 8 heads over the SAME 256 keys ->
// xb rows owned exclusively per block (FETCH 115MB -> ~32MB), waves barrier-free.
// Cross-block merge over 8 key-ranges via f32 partials (bit-identical combine order).

typedef __attribute__((ext_vector_type(8))) short short8;
typedef __attribute__((ext_vector_type(4))) float f32x4;
typedef __attribute__((ext_vector_type(4))) ushort ushort4v;

__device__ __forceinline__ ushort f2bf(float f) {
  uint u = __builtin_bit_cast(uint, f);
  u += 0x7fffu + ((u >> 16) & 1u);
  return (ushort)(u >> 16);
}
__device__ __forceinline__ float bf2f(ushort h) {
  uint u = (uint)h << 16;
  return __builtin_bit_cast(float, u);
}

// ---------------- weight prep: transpose 256x256 f32 [k][n] -> bf16 [n][k] ----------------
__global__ __launch_bounds__(256) void prep_weights(
    const float* __restrict__ Wq, const float* __restrict__ Wk,
    const float* __restrict__ Wv, const float* __restrict__ Wo,
    const float* __restrict__ pWq, const float* __restrict__ pWk,
    const float* __restrict__ pWv, const float* __restrict__ pWo,
    ushort* __restrict__ wt)
{
  __shared__ float tile[64][65];
  const int m = blockIdx.y;          // 0..27
  const int t = blockIdx.x;          // 0..15
  const int tr = (t >> 2) * 64;      // k block
  const int tc = (t & 3) * 64;       // n block
  const float* src;
  if (m < 24) {
    int l = m >> 3, s = (m >> 2) & 1, w = m & 3;
    const float* base = (w == 0) ? Wq : (w == 1) ? Wk : (w == 2) ? Wv : Wo;
    src = base + (size_t)(l * 2 + s) * 65536;
  } else {
    int w = m & 3;
    src = (w == 0) ? pWq : (w == 1) ? pWk : (w == 2) ? pWv : pWo;
  }
  const int tid = threadIdx.x;
  const int cn = tid & 63;
  const int rk = tid >> 6;
#pragma unroll
  for (int j = 0; j < 16; ++j) {
    int kl = rk + j * 4;
    tile[kl][cn] = src[(size_t)(tr + kl) * 256 + tc + cn];
  }
  __syncthreads();
  ushort* dst = wt + (size_t)m * 65536;
#pragma unroll
  for (int j = 0; j < 16; ++j) {
    int nl = rk + j * 4;
    dst[(size_t)(tc + nl) * 256 + tr + cn] = f2bf(tile[cn][nl]);
  }
}

// ---------------- input projection + exact gelu -> bf16, 8 rows/block ----------------
__global__ __launch_bounds__(256) void proj_gelu(
    const float* __restrict__ xv, const float* __restrict__ yt,
    const float* __restrict__ pW, const float* __restrict__ pb,
    ushort* __restrict__ xb)
{
  const int d = threadIdx.x;
  const int row0 = blockIdx.x * 8;
  const float w0 = pW[d], w1 = pW[256 + d], w2 = pW[512 + d], w3 = pW[768 + d];
  const float bz = pb[d];
#pragma unroll
  for (int rr = 0; rr < 8; ++rr) {
    int row = row0 + rr;
    float f0 = xv[(size_t)row * 3 + 0];
    float f1 = xv[(size_t)row * 3 + 1];
    float f2 = xv[(size_t)row * 3 + 2];
    float f3 = yt[row];
    float a = bz + f0 * w0 + f1 * w1 + f2 * w2 + f3 * w3;
    float g = 0.5f * a * (1.f + erff(a * 0.70710678118654752f));
    xb[(size_t)row * 256 + d] = f2bf(g);
  }
}

// ---------------- batched tiny q-projections (f32 A, M=64/32) ----------------
__global__ __launch_bounds__(256) void gemm_q(
    const float* __restrict__ iI, const float* __restrict__ pS,
    const ushort* __restrict__ wt, const float* __restrict__ ibq,
    const float* __restrict__ pbq, ushort* __restrict__ q_all)
{
  const int bq = blockIdx.x;
  const float* A; const ushort* Wt; const float* bias; ushort* out; int M;
  if (bq < 3) { A = iI + bq * 16384; Wt = wt + (size_t)(bq * 8) * 65536; bias = ibq + bq * 512; out = q_all + bq * 16384; M = 64; }
  else        { A = pS; Wt = wt + (size_t)24 * 65536; bias = pbq; out = q_all + 49152; M = 32; }
  const int tid = threadIdx.x;
  const int wave = tid >> 6, lane = tid & 63;
  const int l15 = lane & 15, l4 = lane >> 4, koff = l4 * 8;
  f32x4 acc[4][4];
#pragma unroll
  for (int i = 0; i < 4; ++i)
#pragma unroll
    for (int j = 0; j < 4; ++j) acc[i][j] = (f32x4)0.f;
#pragma unroll
  for (int ks = 0; ks < 8; ++ks) {
    short8 af[4];
#pragma unroll
    for (int mf = 0; mf < 4; ++mf) {
      if (mf * 16 < M) {
        const float* ap = A + (size_t)(mf * 16 + l15) * 256 + ks * 32 + koff;
        float4 f0 = *(const float4*)ap;
        float4 f1 = *(const float4*)(ap + 4);
        short8 sv;
        sv[0] = (short)f2bf(f0.x); sv[1] = (short)f2bf(f0.y);
        sv[2] = (short)f2bf(f0.z); sv[3] = (short)f2bf(f0.w);
        sv[4] = (short)f2bf(f1.x); sv[5] = (short)f2bf(f1.y);
        sv[6] = (short)f2bf(f1.z); sv[7] = (short)f2bf(f1.w);
        af[mf] = sv;
      } else af[mf] = (short8)0;
    }
#pragma unroll
    for (int nf = 0; nf < 4; ++nf) {
      short8 bf = *(const short8*)(Wt + (size_t)(wave * 64 + nf * 16 + l15) * 256 + ks * 32 + koff);
#pragma unroll
      for (int mf = 0; mf < 4; ++mf)
        acc[mf][nf] = __builtin_amdgcn_mfma_f32_16x16x32_bf16(af[mf], bf, acc[mf][nf], 0, 0, 0);
    }
  }
#pragma unroll
  for (int mf = 0; mf < 4; ++mf) {
    if (mf * 16 >= M) continue;
#pragma unroll
    for (int nf = 0; nf < 4; ++nf) {
      int col = wave * 64 + nf * 16 + l15;
      float bcol = bias[col];
#pragma unroll
      for (int r = 0; r < 4; ++r)
        out[(size_t)(mf * 16 + l4 * 4 + r) * 256 + col] = f2bf(acc[mf][nf][r] + bcol);
    }
  }
}

// ---------------- B-panel GEMM: out = epi(A @ W + bias) ----------------
// 1-D grid with XCD-colocating decode: bid = (x&7) + 8*(yz + nyz*(x>>3)).
template <int EPI, bool OUTF32, int COLS>
__global__ __launch_bounds__(COLS * 2, (COLS == 128) ? 4 : 2) void gemm_bp(
    const ushort* __restrict__ A,
    const ushort* __restrict__ Wt0, const ushort* __restrict__ Wt1, const ushort* __restrict__ Wt2,
    const float* __restrict__ b0, const float* __restrict__ b1, const float* __restrict__ b2,
    void* __restrict__ o0, void* __restrict__ o1, void* __restrict__ o2,
    const float* __restrict__ lng, const float* __restrict__ lnb,
    int ny, int nyz)
{
  constexpr int WC = COLS / 64;
  constexpr int PS = COLS * 64;
  constexpr int ROWB = COLS * 2;
  __shared__ __align__(16) char Bs[4 * PS];
  __shared__ float redbuf[(EPI == 3) ? 1280 : 4];
  const int bid = blockIdx.x;
  const int rest = bid >> 3;
  const int yz = rest % nyz;
  const int bx = ((rest / nyz) << 3) | (bid & 7);
  const int y = yz % ny;
  const int z = yz / ny;
  const ushort* Wt = (z == 0) ? Wt0 : ((z == 1) ? Wt1 : Wt2);
  const float* bias = (z == 0) ? b0 : ((z == 1) ? b1 : b2);
  void* outp = (z == 0) ? o0 : ((z == 1) ? o1 : o2);
  const int pcol = y * COLS;

  const int tid = threadIdx.x;
  const int wave = tid >> 6, lane = tid & 63;
  const int wc = wave % WC, wr = wave / WC;
  const int l15 = lane & 15, l4 = lane >> 4;
  const int row0 = bx * 128;
  const int sn = tid >> 1, sseg = tid & 1;

  f32x4 acc[4][4];
#pragma unroll
  for (int i = 0; i < 4; ++i)
#pragma unroll
    for (int j = 0; j < 4; ++j) acc[i][j] = (f32x4)0.f;

#pragma unroll
  for (int half = 0; half < 2; ++half) {
    if (half) __syncthreads();
    {
      const ushort* src = Wt + (size_t)(pcol + sn) * 256 + half * 128 + sseg * 64;
#pragma unroll
      for (int c = 0; c < 8; ++c) {
        uint4 w = *(const uint4*)(src + c * 8);
        int plane = sseg * 2 + (c >> 2);
        char* dst = Bs + plane * PS + sn * 64 + (((c & 3) * 16) ^ (((sn >> 1) & 3) << 4));
        *(uint4*)dst = w;
      }
    }
    __syncthreads();
#pragma unroll
    for (int ks = 0; ks < 4; ++ks) {
      short8 af[4];
#pragma unroll
      for (int mfa = 0; mfa < 4; ++mfa)
        af[mfa] = *(const short8*)(A + (size_t)(row0 + wr * 64 + mfa * 16 + l15) * 256 + half * 128 + ks * 32 + l4 * 8);
#pragma unroll
      for (int nfb = 0; nfb < 4; ++nfb) {
        int n = wc * 64 + nfb * 16 + l15;
        short8 bf = *(const short8*)(Bs + ks * PS + n * 64 + ((l4 * 16) ^ (((n >> 1) & 3) << 4)));
#pragma unroll
        for (int mfa = 0; mfa < 4; ++mfa)
          acc[mfa][nfb] = __builtin_amdgcn_mfma_f32_16x16x32_bf16(bf, af[mfa], acc[mfa][nfb], 0, 0, 0);
      }
    }
  }

  if constexpr (EPI == 0) {
    __syncthreads();
#pragma unroll
    for (int nfb = 0; nfb < 4; ++nfb) {
      f32x4 bv = *(const f32x4*)(bias + pcol + wc * 64 + nfb * 16 + l4 * 4);
      int colb = wc * 128 + nfb * 32 + l4 * 8;
#pragma unroll
      for (int mfa = 0; mfa < 4; ++mfa) {
        int row = wr * 64 + mfa * 16 + l15;
        ushort4v pk;
#pragma unroll
        for (int i = 0; i < 4; ++i) pk[i] = f2bf(acc[mfa][nfb][i] + bv[i]);
        *(ushort4v*)(Bs + row * ROWB + (colb ^ ((row & 7) << 4))) = pk;
      }
    }
    __syncthreads();
    const int srow = tid >> 2, seg = tid & 3;
#pragma unroll
    for (int rr = 0; rr < 2; ++rr) {
      int row = srow + rr * 64;
      int x = (row & 7) << 4;
      ushort* gdst = (ushort*)outp + (size_t)(row0 + row) * 256 + pcol;
#pragma unroll
      for (int it = 0; it < 4; ++it) {
        int colb = seg * 16 + it * 64;
        uint4 v = *(const uint4*)(Bs + row * ROWB + (colb ^ x));
        *(uint4*)(gdst + colb / 2) = v;
      }
    }
  } else {
    float* red1 = redbuf;
    float* red2 = redbuf + 512;
    float* mv_ = redbuf + 1024;
    float* rv_ = redbuf + 1152;
    float s1[4] = {0.f, 0.f, 0.f, 0.f}, s2[4] = {0.f, 0.f, 0.f, 0.f};
#pragma unroll
    for (int nfb = 0; nfb < 4; ++nfb) {
      int col0 = wc * 64 + nfb * 16 + l4 * 4;
      f32x4 bv = *(const f32x4*)(bias + col0);
#pragma unroll
      for (int mfa = 0; mfa < 4; ++mfa) {
        size_t row = (size_t)row0 + wr * 64 + mfa * 16 + l15;
        ushort4v rz = *(const ushort4v*)(A + row * 256 + col0);
#pragma unroll
        for (int i = 0; i < 4; ++i) {
          float zz = bf2f(rz[i]) + fmaxf(acc[mfa][nfb][i] + bv[i], 0.f);
          acc[mfa][nfb][i] = zz;
          s1[mfa] += zz;
          s2[mfa] += zz * zz;
        }
      }
    }
#pragma unroll
    for (int mfa = 0; mfa < 4; ++mfa) {
      s1[mfa] += __shfl_xor(s1[mfa], 16); s1[mfa] += __shfl_xor(s1[mfa], 32);
      s2[mfa] += __shfl_xor(s2[mfa], 16); s2[mfa] += __shfl_xor(s2[mfa], 32);
    }
    if (l4 == 0) {
#pragma unroll
      for (int mfa = 0; mfa < 4; ++mfa) {
        red1[wc * 128 + wr * 64 + mfa * 16 + l15] = s1[mfa];
        red2[wc * 128 + wr * 64 + mfa * 16 + l15] = s2[mfa];
      }
    }
    __syncthreads();
    if (tid < 128) {
      float m1 = red1[tid] + red1[128 + tid] + red1[256 + tid] + red1[384 + tid];
      float m2 = red2[tid] + red2[128 + tid] + red2[256 + tid] + red2[384 + tid];
      float mean = m1 * 0.00390625f;
      float var = m2 * 0.00390625f - mean * mean;
      mv_[tid] = mean;
      rv_[tid] = rsqrtf(var + 1e-5f);
    }
    __syncthreads();
#pragma unroll
    for (int nfb = 0; nfb < 4; ++nfb) {
      int col0 = wc * 64 + nfb * 16 + l4 * 4;
      f32x4 gg = *(const f32x4*)(lng + col0);
      f32x4 bb = *(const f32x4*)(lnb + col0);
      int colb = col0 * 2;
#pragma unroll
      for (int mfa = 0; mfa < 4; ++mfa) {
        int lr = wr * 64 + mfa * 16 + l15;
        float mean = mv_[lr], rs = rv_[lr];
        if constexpr (OUTF32) {
          f32x4 w;
#pragma unroll
          for (int i = 0; i < 4; ++i) w[i] = (acc[mfa][nfb][i] - mean) * rs * gg[i] + bb[i];
          *(f32x4*)((float*)outp + ((size_t)row0 + lr) * 256 + col0) = w;
        } else {
          ushort4v pk;
#pragma unroll
          for (int i = 0; i < 4; ++i) pk[i] = f2bf((acc[mfa][nfb][i] - mean) * rs * gg[i] + bb[i]);
          *(ushort4v*)(Bs + lr * ROWB + (colb ^ ((lr & 7) << 4))) = pk;
        }
      }
    }
    if constexpr (!OUTF32) {
      __syncthreads();
      const int srow = tid >> 2, seg = tid & 3;
      int x = (srow & 7) << 4;
      ushort* gdst = (ushort*)outp + (size_t)(row0 + srow) * 256;
#pragma unroll
      for (int it = 0; it < 8; ++it) {
        int colb = seg * 16 + it * 64;
        uint4 v = *(const uint4*)(Bs + srow * ROWB + (colb ^ x));
        *(uint4*)(gdst + colb / 2) = v;
      }
    }
  }
}

// ---------------- attn_split: K/V-projecting flash attention over one key-range ----------
// grid(b=32, kr=8), block 512 = 8 waves = 8 HEADS over the SAME 256 keys (kr*256..).
// All waves read the same xb rows (exclusive per block -> HBM fetch = 32MB total);
// zero barriers. Per wave: project K (per-nf 16-key staging) and V (full V^T tile),
// QK^T / online softmax / PV (verbatim math), then write f32 partials (M,L,O).
template <int MF>
__global__ __launch_bounds__(512) void attn_split(
    const ushort* __restrict__ qb, const ushort* __restrict__ xbuf,
    const ushort* __restrict__ wk, const float* __restrict__ bk,
    const ushort* __restrict__ wv, const float* __restrict__ bv,
    const float* __restrict__ mask,
    float* __restrict__ Opart, float* __restrict__ Mpart, float* __restrict__ Lpart)
{
  __shared__ __align__(16) ushort Ps[8][64][72];    // 72KB: P tiles
  __shared__ __align__(16) ushort Vt[8][32][72];    // 36KB: V^T tiles
  __shared__ __align__(16) ushort Kc16[8][16][40];  // 10KB: per-nf projected K
  const int b = blockIdx.x, kr = blockIdx.y;
  const int tid = threadIdx.x;
  const int w = tid >> 6, lane = tid & 63;  // w = head
  const int l15 = lane & 15, l4 = lane >> 4;
  const int koff = l4 * 8;
  const int kvbase = b * 2048;
  const int h = w;
  const int p = (b * 8 + h) * 8 + kr;

  short8 qf[MF];
#pragma unroll
  for (int mf = 0; mf < MF; ++mf)
    qf[mf] = *(const short8*)(qb + (size_t)(mf * 16 + l15) * 256 + h * 32 + koff);

  f32x4 bkv[2], bvv[2];
#pragma unroll
  for (int nfb = 0; nfb < 2; ++nfb) {
    bkv[nfb] = *(const f32x4*)(bk + h * 32 + nfb * 16 + l4 * 4);
    bvv[nfb] = *(const f32x4*)(bv + h * 32 + nfb * 16 + l4 * 4);
  }

  f32x4 Oa[MF][2];
  float Mr[MF][4], Lr[MF][4];
#pragma unroll
  for (int mf = 0; mf < MF; ++mf) {
    Oa[mf][0] = (f32x4)0.f; Oa[mf][1] = (f32x4)0.f;
#pragma unroll
    for (int r = 0; r < 4; ++r) { Mr[mf][r] = -1e30f; Lr[mf][r] = 0.f; }
  }

  for (int c = 0; c < 4; ++c) {
    const int kc = kr * 256 + c * 64;
    // ---- project K,V for the 64-key chunk (swapped MFMA: lane=(key l15, col l4*4+i)) ----
    f32x4 ak[4][2], av[4][2];
#pragma unroll
    for (int i = 0; i < 4; ++i) {
      ak[i][0] = (f32x4)0.f; ak[i][1] = (f32x4)0.f;
      av[i][0] = (f32x4)0.f; av[i][1] = (f32x4)0.f;
    }
#pragma unroll
    for (int ks = 0; ks < 8; ++ks) {
      short8 af[4];
#pragma unroll
      for (int mfa = 0; mfa < 4; ++mfa)
        af[mfa] = *(const short8*)(xbuf + (size_t)(kvbase + kc + mfa * 16 + l15) * 256 + ks * 32 + koff);
#pragma unroll
      for (int nfb = 0; nfb < 2; ++nfb) {
        int n = h * 32 + nfb * 16 + l15;
        short8 wkf = *(const short8*)(wk + (size_t)n * 256 + ks * 32 + koff);
        short8 wvf = *(const short8*)(wv + (size_t)n * 256 + ks * 32 + koff);
#pragma unroll
        for (int mfa = 0; mfa < 4; ++mfa) {
          ak[mfa][nfb] = __builtin_amdgcn_mfma_f32_16x16x32_bf16(wkf, af[mfa], ak[mfa][nfb], 0, 0, 0);
          av[mfa][nfb] = __builtin_amdgcn_mfma_f32_16x16x32_bf16(wvf, af[mfa], av[mfa][nfb], 0, 0, 0);
        }
      }
    }
    // stage V^T: Vt[col][key] bf16 (+bias) — wave-private, in-order
#pragma unroll
    for (int nfb = 0; nfb < 2; ++nfb)
#pragma unroll
      for (int mfa = 0; mfa < 4; ++mfa)
#pragma unroll
        for (int i = 0; i < 4; ++i)
          Vt[w][nfb * 16 + l4 * 4 + i][mfa * 16 + l15] = f2bf(av[mfa][nfb][i] + bvv[nfb][i]);

    // ---- per-nf: stage K 16-key group, read B-frag, QK^T MFMAs ----
    f32x4 S[MF][4];
#pragma unroll
    for (int nf = 0; nf < 4; ++nf) {
#pragma unroll
      for (int nfb = 0; nfb < 2; ++nfb) {
        ushort4v pk;
#pragma unroll
        for (int i = 0; i < 4; ++i) pk[i] = f2bf(ak[nf][nfb][i] + bkv[nfb][i]);
        *(ushort4v*)&Kc16[w][l15][nfb * 16 + l4 * 4] = pk;
      }
      short8 kf = *(const short8*)&Kc16[w][l15][koff];
#pragma unroll
      for (int mf = 0; mf < MF; ++mf)
        S[mf][nf] = __builtin_amdgcn_mfma_f32_16x16x32_bf16(qf[mf], kf, (f32x4)0.f, 0, 0, 0);
    }
    float mv[4];
#pragma unroll
    for (int nf = 0; nf < 4; ++nf)
      mv[nf] = mask[(size_t)b * 2048 + kc + nf * 16 + l15];
#pragma unroll
    for (int mf = 0; mf < MF; ++mf)
#pragma unroll
      for (int nf = 0; nf < 4; ++nf)
#pragma unroll
        for (int r = 0; r < 4; ++r) {
          float s = S[mf][nf][r] * 0.0625f;
          S[mf][nf][r] = (mv[nf] != 0.f) ? s : -1e4f;
        }
#pragma unroll
    for (int mf = 0; mf < MF; ++mf)
#pragma unroll
      for (int r = 0; r < 4; ++r) {
        float pm = fmaxf(fmaxf(S[mf][0][r], S[mf][1][r]), fmaxf(S[mf][2][r], S[mf][3][r]));
        pm = fmaxf(pm, __shfl_xor(pm, 1));
        pm = fmaxf(pm, __shfl_xor(pm, 2));
        pm = fmaxf(pm, __shfl_xor(pm, 4));
        pm = fmaxf(pm, __shfl_xor(pm, 8));
        float Mnew = fmaxf(Mr[mf][r], pm);
        float corr = __expf(Mr[mf][r] - Mnew);
        Mr[mf][r] = Mnew;
        float rs = 0.f;
#pragma unroll
        for (int nf = 0; nf < 4; ++nf) {
          float pp = __expf(S[mf][nf][r] - Mnew);
          S[mf][nf][r] = pp;
          rs += pp;
        }
        rs += __shfl_xor(rs, 1);
        rs += __shfl_xor(rs, 2);
        rs += __shfl_xor(rs, 4);
        rs += __shfl_xor(rs, 8);
        Lr[mf][r] = Lr[mf][r] * corr + rs;
        Oa[mf][0][r] *= corr;
        Oa[mf][1][r] *= corr;
      }
#pragma unroll
    for (int mf = 0; mf < MF; ++mf)
#pragma unroll
      for (int nf = 0; nf < 4; ++nf)
#pragma unroll
        for (int r = 0; r < 4; ++r)
          Ps[w][mf * 16 + l4 * 4 + r][nf * 16 + l15] = f2bf(S[mf][nf][r]);
#pragma unroll
    for (int ks = 0; ks < 2; ++ks) {
      short8 pf[MF];
#pragma unroll
      for (int mf = 0; mf < MF; ++mf)
        pf[mf] = *(const short8*)&Ps[w][mf * 16 + l15][ks * 32 + koff];
#pragma unroll
      for (int nf2 = 0; nf2 < 2; ++nf2) {
        short8 vf = *(const short8*)&Vt[w][nf2 * 16 + l15][ks * 32 + koff];
#pragma unroll
        for (int mf = 0; mf < MF; ++mf)
          Oa[mf][nf2] = __builtin_amdgcn_mfma_f32_16x16x32_bf16(pf[mf], vf, Oa[mf][nf2], 0, 0, 0);
      }
    }
  }

  // ---- write f32 partials (no barriers anywhere) ----
#pragma unroll
  for (int mf = 0; mf < MF; ++mf)
#pragma unroll
    for (int r = 0; r < 4; ++r) {
      int row = mf * 16 + l4 * 4 + r;
      if (l15 == 0) {
        Mpart[(size_t)p * 64 + row] = Mr[mf][r];
        Lpart[(size_t)p * 64 + row] = Lr[mf][r];
      }
#pragma unroll
      for (int nf2 = 0; nf2 < 2; ++nf2)
        Opart[(size_t)p * 2048 + row * 32 + nf2 * 16 + l15] = Oa[mf][nf2][r];
    }
}

// ---------------- attn_merge: combine 8 key-range partials + residual -> bf16 ----------
// grid(b=32, h=8), 256 thr. Same combine order (s=0..7) and arithmetic as the old
// in-block merge -> bit-identical output.
template <int MF>
__global__ __launch_bounds__(256) void attn_merge(
    const ushort* __restrict__ qb, const float* __restrict__ Opart,
    const float* __restrict__ Mpart, const float* __restrict__ Lpart,
    ushort* __restrict__ O)
{
  const int b = blockIdx.x, h = blockIdx.y;
  const int tid = threadIdx.x;
  const int NQ = MF * 16;
  const int row = tid >> 2, dg = tid & 3;
  if (row >= NQ) return;
  const size_t pb = ((size_t)(b * 8 + h)) * 8;
  float mm = -1e30f;
#pragma unroll
  for (int s = 0; s < 8; ++s) mm = fmaxf(mm, Mpart[(pb + s) * 64 + row]);
  float den = 0.f, es[8];
#pragma unroll
  for (int s = 0; s < 8; ++s) {
    es[s] = __expf(Mpart[(pb + s) * 64 + row] - mm);
    den += Lpart[(pb + s) * 64 + row] * es[s];
  }
  float invden = 1.f / den;
  ushort4v pk0, pk1;
#pragma unroll
  for (int i = 0; i < 8; ++i) {
    int d = dg * 8 + i;
    float num = 0.f;
#pragma unroll
    for (int s = 0; s < 8; ++s) num += Opart[(pb + s) * 2048 + row * 32 + d] * es[s];
    float qv = bf2f(qb[(size_t)row * 256 + h * 32 + d]);
    ushort res = f2bf(qv + num * invden);
    if (i < 4) pk0[i] = res; else pk1[i - 4] = res;
  }
  ushort* dst = O + (size_t)(b * NQ + row) * 256 + h * 32 + dg * 8;
  *(ushort4v*)dst = pk0;
  *(ushort4v*)(dst + 4) = pk1;
}

// ---------------- mab1_fused (r10 config): q-proj + attention(nk=64) + LN0 + Wo + LN1 ----
__global__ __launch_bounds__(512, 4) void mab1_fused(
    const ushort* __restrict__ xb, const ushort* __restrict__ wq,
    const float* __restrict__ bq,
    const ushort* __restrict__ kb, const ushort* __restrict__ vb,
    const ushort* __restrict__ wo, const float* __restrict__ bo,
    const float* __restrict__ g0, const float* __restrict__ b0v,
    const float* __restrict__ g1, const float* __restrict__ b1v,
    ushort* __restrict__ outb)
{
  __shared__ __align__(16) ushort Qs[8][64][40];
  __shared__ __align__(16) ushort Psh[8][16][40];
  __shared__ __align__(16) ushort Vth[8][32][40];
  __shared__ float red1[8][64], red2[8][64], mv_[64], rv_[64];
  ushort* o_s = &Qs[0][0][0];
  constexpr int OS = 264;

  const int qt = blockIdx.x, b = blockIdx.y;
  const int tid = threadIdx.x;
  const int w = tid >> 6, lane = tid & 63;
  const int l15 = lane & 15, l4 = lane >> 4;
  const int koff = l4 * 8;
  const size_t row0 = (size_t)b * 2048 + qt * 64;
  const int kvbase = b * 64;
  const int h = w;

  short8 kf[4];
#pragma unroll
  for (int nf = 0; nf < 4; ++nf)
    kf[nf] = *(const short8*)(kb + (size_t)(kvbase + nf * 16 + l15) * 256 + h * 32 + koff);
  const int key = lane & 31, dh2 = lane >> 5;
  short8 vvB0, vvB1;
  {
    const ushort* vsrcA = vb + (size_t)(kvbase + key) * 256 + h * 32 + dh2 * 16;
    const ushort* vsrcB = vb + (size_t)(kvbase + 32 + key) * 256 + h * 32 + dh2 * 16;
    short8 vvA0 = *(const short8*)vsrcA;
    short8 vvA1 = *(const short8*)(vsrcA + 8);
    vvB0 = *(const short8*)vsrcB;
    vvB1 = *(const short8*)(vsrcB + 8);
#pragma unroll
    for (int j = 0; j < 8; ++j) Vth[w][dh2 * 16 + j][key] = (ushort)vvA0[j];
#pragma unroll
    for (int j = 0; j < 8; ++j) Vth[w][dh2 * 16 + 8 + j][key] = (ushort)vvA1[j];
  }

  {
    f32x4 qa[4][2];
#pragma unroll
    for (int i = 0; i < 4; ++i) { qa[i][0] = (f32x4)0.f; qa[i][1] = (f32x4)0.f; }
#pragma unroll
    for (int ks = 0; ks < 8; ++ks) {
      short8 af[4];
#pragma unroll
      for (int mfa = 0; mfa < 4; ++mfa)
        af[mfa] = *(const short8*)(xb + (row0 + mfa * 16 + l15) * 256 + ks * 32 + koff);
#pragma unroll
      for (int nfb = 0; nfb < 2; ++nfb) {
        int n = w * 32 + nfb * 16 + l15;
        short8 bf = *(const short8*)(wq + (size_t)n * 256 + ks * 32 + koff);
#pragma unroll
        for (int mfa = 0; mfa < 4; ++mfa)
          qa[mfa][nfb] = __builtin_amdgcn_mfma_f32_16x16x32_bf16(bf, af[mfa], qa[mfa][nfb], 0, 0, 0);
      }
    }
#pragma unroll
    for (int nfb = 0; nfb < 2; ++nfb) {
      f32x4 bvq = *(const f32x4*)(bq + w * 32 + nfb * 16 + l4 * 4);
#pragma unroll
      for (int mfa = 0; mfa < 4; ++mfa) {
        ushort4v pk;
#pragma unroll
        for (int i = 0; i < 4; ++i) pk[i] = f2bf(qa[mfa][nfb][i] + bvq[i]);
        *(ushort4v*)&Qs[w][mfa * 16 + l15][nfb * 16 + l4 * 4] = pk;
      }
    }
  }

  short8 qf[4];
#pragma unroll
  for (int mf = 0; mf < 4; ++mf)
    qf[mf] = *(const short8*)&Qs[w][mf * 16 + l15][koff];

  f32x4 S[4][4];
#pragma unroll
  for (int nf = 0; nf < 4; ++nf) {
#pragma unroll
    for (int mf = 0; mf < 4; ++mf)
      S[mf][nf] = __builtin_amdgcn_mfma_f32_16x16x32_bf16(qf[mf], kf[nf], (f32x4)0.f, 0, 0, 0);
  }
  float Lr[4][4];
#pragma unroll
  for (int mf = 0; mf < 4; ++mf)
#pragma unroll
    for (int r = 0; r < 4; ++r) {
      float pm = fmaxf(fmaxf(S[mf][0][r], S[mf][1][r]), fmaxf(S[mf][2][r], S[mf][3][r])) * 0.0625f;
      pm = fmaxf(pm, __shfl_xor(pm, 1));
      pm = fmaxf(pm, __shfl_xor(pm, 2));
      pm = fmaxf(pm, __shfl_xor(pm, 4));
      pm = fmaxf(pm, __shfl_xor(pm, 8));
      float rs = 0.f;
#pragma unroll
      for (int nf = 0; nf < 4; ++nf) {
        float pp = __expf(S[mf][nf][r] * 0.0625f - pm);
        S[mf][nf][r] = pp;
        rs += pp;
      }
      rs += __shfl_xor(rs, 1);
      rs += __shfl_xor(rs, 2);
      rs += __shfl_xor(rs, 4);
      rs += __shfl_xor(rs, 8);
      Lr[mf][r] = rs;
    }

  f32x4 Oa[4][2];
#pragma unroll
  for (int mf = 0; mf < 4; ++mf) { Oa[mf][0] = (f32x4)0.f; Oa[mf][1] = (f32x4)0.f; }
#pragma unroll
  for (int mf = 0; mf < 4; ++mf) {
#pragma unroll
    for (int nf = 0; nf < 2; ++nf)
#pragma unroll
      for (int r = 0; r < 4; ++r)
        Psh[w][l4 * 4 + r][nf * 16 + l15] = f2bf(S[mf][nf][r]);
    short8 pf = *(const short8*)&Psh[w][l15][koff];
#pragma unroll
    for (int nf2 = 0; nf2 < 2; ++nf2) {
      short8 vf = *(const short8*)&Vth[w][nf2 * 16 + l15][koff];
      Oa[mf][nf2] = __builtin_amdgcn_mfma_f32_16x16x32_bf16(pf, vf, Oa[mf][nf2], 0, 0, 0);
    }
  }
#pragma unroll
  for (int j = 0; j < 8; ++j) Vth[w][dh2 * 16 + j][key] = (ushort)vvB0[j];
#pragma unroll
  for (int j = 0; j < 8; ++j) Vth[w][dh2 * 16 + 8 + j][key] = (ushort)vvB1[j];
#pragma unroll
  for (int mf = 0; mf < 4; ++mf) {
#pragma unroll
    for (int nf = 0; nf < 2; ++nf)
#pragma unroll
      for (int r = 0; r < 4; ++r)
        Psh[w][l4 * 4 + r][nf * 16 + l15] = f2bf(S[mf][nf + 2][r]);
    short8 pf = *(const short8*)&Psh[w][l15][koff];
#pragma unroll
    for (int nf2 = 0; nf2 < 2; ++nf2) {
      short8 vf = *(const short8*)&Vth[w][nf2 * 16 + l15][koff];
      Oa[mf][nf2] = __builtin_amdgcn_mfma_f32_16x16x32_bf16(pf, vf, Oa[mf][nf2], 0, 0, 0);
    }
  }

  {
    float s1[4][4], s2[4][4];
#pragma unroll
    for (int mf = 0; mf < 4; ++mf)
#pragma unroll
      for (int r = 0; r < 4; ++r) {
        float invL = 1.f / Lr[mf][r];
        s1[mf][r] = 0.f; s2[mf][r] = 0.f;
#pragma unroll
        for (int nf2 = 0; nf2 < 2; ++nf2) {
          float qv = bf2f(Qs[w][mf * 16 + l4 * 4 + r][nf2 * 16 + l15]);
          float z = qv + Oa[mf][nf2][r] * invL;
          Oa[mf][nf2][r] = z;
          s1[mf][r] += z;
          s2[mf][r] += z * z;
        }
#pragma unroll
        for (int off = 1; off < 16; off <<= 1) {
          s1[mf][r] += __shfl_xor(s1[mf][r], off);
          s2[mf][r] += __shfl_xor(s2[mf][r], off);
        }
        if (l15 == 0) {
          int row = mf * 16 + l4 * 4 + r;
          red1[w][row] = s1[mf][r];
          red2[w][row] = s2[mf][r];
        }
      }
  }
  __syncthreads();
  if (tid < 64) {
    float m1 = 0.f, m2 = 0.f;
#pragma unroll
    for (int s = 0; s < 8; ++s) { m1 += red1[s][tid]; m2 += red2[s][tid]; }
    float mean = m1 * 0.00390625f;
    float var = m2 * 0.00390625f - mean * mean;
    mv_[tid] = mean;
    rv_[tid] = rsqrtf(var + 1e-5f);
  }
  __syncthreads();
#pragma unroll
  for (int nf2 = 0; nf2 < 2; ++nf2) {
    int col = h * 32 + nf2 * 16 + l15;
    float gc = g0[col], bc = b0v[col];
#pragma unroll
    for (int mf = 0; mf < 4; ++mf)
#pragma unroll
      for (int r = 0; r < 4; ++r) {
        int row = mf * 16 + l4 * 4 + r;
        float v = (Oa[mf][nf2][r] - mv_[row]) * rv_[row] * gc + bc;
        o_s[row * OS + col] = f2bf(v);
      }
  }
  __syncthreads();

  f32x4 oa[4][2];
#pragma unroll
  for (int i = 0; i < 4; ++i) { oa[i][0] = (f32x4)0.f; oa[i][1] = (f32x4)0.f; }
#pragma unroll
  for (int ks = 0; ks < 8; ++ks) {
    short8 af[4];
#pragma unroll
    for (int mfa = 0; mfa < 4; ++mfa)
      af[mfa] = *(const short8*)&o_s[(mfa * 16 + l15) * OS + ks * 32 + koff];
#pragma unroll
    for (int nfb = 0; nfb < 2; ++nfb) {
      int n = w * 32 + nfb * 16 + l15;
      short8 bf = *(const short8*)(wo + (size_t)n * 256 + ks * 32 + koff);
#pragma unroll
      for (int mfa = 0; mfa < 4; ++mfa)
        oa[mfa][nfb] = __builtin_amdgcn_mfma_f32_16x16x32_bf16(bf, af[mfa], oa[mfa][nfb], 0, 0, 0);
    }
  }
  float t1[4] = {0.f, 0.f, 0.f, 0.f}, t2[4] = {0.f, 0.f, 0.f, 0.f};
#pragma unroll
  for (int nfb = 0; nfb < 2; ++nfb) {
    int col0 = w * 32 + nfb * 16 + l4 * 4;
    f32x4 bvo = *(const f32x4*)(bo + col0);
#pragma unroll
    for (int mfa = 0; mfa < 4; ++mfa) {
      int row = mfa * 16 + l15;
      ushort4v rz = *(const ushort4v*)&o_s[row * OS + col0];
#pragma unroll
      for (int i = 0; i < 4; ++i) {
        float zz = bf2f(rz[i]) + fmaxf(oa[mfa][nfb][i] + bvo[i], 0.f);
        oa[mfa][nfb][i] = zz;
        t1[mfa] += zz;
        t2[mfa] += zz * zz;
      }
    }
  }
#pragma unroll
  for (int mfa = 0; mfa < 4; ++mfa) {
    t1[mfa] += __shfl_xor(t1[mfa], 16); t1[mfa] += __shfl_xor(t1[mfa], 32);
    t2[mfa] += __shfl_xor(t2[mfa], 16); t2[mfa] += __shfl_xor(t2[mfa], 32);
  }
  if (l4 == 0) {
#pragma unroll
    for (int mfa = 0; mfa < 4; ++mfa) {
      red1[w][mfa * 16 + l15] = t1[mfa];
      red2[w][mfa * 16 + l15] = t2[mfa];
    }
  }
  __syncthreads();
  if (tid < 64) {
    float m1 = 0.f, m2 = 0.f;
#pragma unroll
    for (int s = 0; s < 8; ++s) { m1 += red1[s][tid]; m2 += red2[s][tid]; }
    float mean = m1 * 0.00390625f;
    float var = m2 * 0.00390625f - mean * mean;
    mv_[tid] = mean;
    rv_[tid] = rsqrtf(var + 1e-5f);
  }
  __syncthreads();
#pragma unroll
  for (int nfb = 0; nfb < 2; ++nfb) {
    int col0 = w * 32 + nfb * 16 + l4 * 4;
    f32x4 gg = *(const f32x4*)(g1 + col0);
    f32x4 bb = *(const f32x4*)(b1v + col0);
#pragma unroll
    for (int mfa = 0; mfa < 4; ++mfa) {
      int row = mfa * 16 + l15;
      ushort4v pk;
#pragma unroll
      for (int i = 0; i < 4; ++i)
        pk[i] = f2bf((oa[mfa][nfb][i] - mv_[row]) * rv_[row] * gg[i] + bb[i]);
      *(ushort4v*)&o_s[row * OS + col0] = pk;
    }
  }
  __syncthreads();
  {
    const int r_ = tid >> 3, sg = tid & 7;
    ushort* gdst = outb + (row0 + r_) * 256 + sg * 32;
    const ushort* src = &o_s[r_ * OS + sg * 32];
#pragma unroll
    for (int it = 0; it < 4; ++it) {
      uint4 v = *(const uint4*)(src + it * 8);
      *(uint4*)(gdst + it * 8) = v;
    }
  }
}

// ---------------- small LayerNorm: bf16 in/out, wave per row ----------------
__global__ __launch_bounds__(256) void ln4(
    const ushort* __restrict__ in, ushort* __restrict__ out,
    const float* __restrict__ g, const float* __restrict__ bb)
{
  const int w = threadIdx.x >> 6, lane = threadIdx.x & 63;
  const size_t row = (size_t)blockIdx.x * 4 + w;
  ushort4v u = *(const ushort4v*)(in + row * 256 + lane * 4);
  float v[4];
#pragma unroll
  for (int i = 0; i < 4; ++i) v[i] = bf2f(u[i]);
  float s1 = v[0] + v[1] + v[2] + v[3];
  float s2 = v[0] * v[0] + v[1] * v[1] + v[2] * v[2] + v[3] * v[3];
#pragma unroll
  for (int off = 1; off < 64; off <<= 1) {
    s1 += __shfl_xor(s1, off);
    s2 += __shfl_xor(s2, off);
  }
  float mean = s1 * 0.00390625f;
  float var = s2 * 0.00390625f - mean * mean;
  float rs = rsqrtf(var + 1e-5f);
  f32x4 gg = *(const f32x4*)(g + lane * 4);
  f32x4 bv = *(const f32x4*)(bb + lane * 4);
  ushort4v p;
#pragma unroll
  for (int i = 0; i < 4; ++i) p[i] = f2bf((v[i] - mean) * rs * gg[i] + bv[i]);
  *(ushort4v*)(out + row * 256 + lane * 4) = p;
}

extern "C" void kernel_launch(void* const* d_in, const int* in_sizes, int n_in,
                              void* d_out, int out_size, void* d_ws, size_t ws_size,
                              hipStream_t stream) {
  const float* xv = (const float*)d_in[0];
  const float* yt = (const float*)d_in[1];
  const float* pmask = (const float*)d_in[2];
  const float* prW = (const float*)d_in[3];
  const float* prb = (const float*)d_in[4];
  const float* iI = (const float*)d_in[5];
  const float* iWq = (const float*)d_in[6];
  const float* ibq = (const float*)d_in[7];
  const float* iWk = (const float*)d_in[8];
  const float* ibk = (const float*)d_in[9];
  const float* iWv = (const float*)d_in[10];
  const float* ibv = (const float*)d_in[11];
  const float* iWo = (const float*)d_in[12];
  const float* ibo = (const float*)d_in[13];
  const float* ig0 = (const float*)d_in[14];
  const float* ib0 = (const float*)d_in[15];
  const float* ig1 = (const float*)d_in[16];
  const float* ib1 = (const float*)d_in[17];
  const float* pS = (const float*)d_in[18];
  const float* pWq = (const float*)d_in[19];
  const float* pbq = (const float*)d_in[20];
  const float* pWk = (const float*)d_in[21];
  const float* pbk = (const float*)d_in[22];
  const float* pWv = (const float*)d_in[23];
  const float* pbv = (const float*)d_in[24];
  const float* pWo = (const float*)d_in[25];
  const float* pbo = (const float*)d_in[26];
  const float* pg0 = (const float*)d_in[27];
  const float* pb0 = (const float*)d_in[28];
  const float* pg1 = (const float*)d_in[29];
  const float* pb1 = (const float*)d_in[30];

  char* ws = (char*)d_ws;
  if (ws_size < 172621824u) return;
  ushort* xb = (ushort*)(ws + 0);              // 32MB (B*N x 256)
  ushort* ob = (ushort*)(ws + 33554432);       // 32MB (attn/LN scratch)
  ushort* hb = (ushort*)(ws + 67108864);       // 1MB  (B*NI x 256)
  ushort* kbw = (ushort*)(ws + 101711872);     // 32MB (mab1 K; also attn partials)
  ushort* vbw = (ushort*)(ws + 135266304);     // 32MB (mab1 V)
  ushort* wt = (ushort*)(ws + 168820736);      // 3.5MB transposed weights
  ushort* q_all = (ushort*)(ws + 172490752);   // 112KB tiny-q outputs
  // attention split partials overlay the kbw region (dead at attn time):
  float* Opart = (float*)(ws + 101711872);           // 16MB (2048 x 2048 f32)
  float* Mpart = (float*)(ws + 101711872 + 16777216);  // 512KB
  float* Lpart = Mpart + 131072;                        // 512KB

  prep_weights<<<dim3(16, 28), 256, 0, stream>>>(iWq, iWk, iWv, iWo, pWq, pWk, pWv, pWo, wt);
  proj_gelu<<<8192, 256, 0, stream>>>(xv, yt, prW, prb, xb);
  gemm_q<<<4, 256, 0, stream>>>(iI, pS, wt, ibq, pbq, q_all);

  for (int l = 0; l < 3; ++l) {
    const int s0 = l * 2, s1 = l * 2 + 1;
    const ushort* wk = wt + (size_t)(l * 8 + 1) * 65536;
    const ushort* wv = wt + (size_t)(l * 8 + 2) * 65536;
    const ushort* wo0 = wt + (size_t)(l * 8 + 3) * 65536;
    const ushort* wq1 = wt + (size_t)(l * 8 + 4) * 65536;
    const ushort* wk1 = wt + (size_t)(l * 8 + 5) * 65536;
    const ushort* wv1 = wt + (size_t)(l * 8 + 6) * 65536;
    const ushort* wo1 = wt + (size_t)(l * 8 + 7) * 65536;
    // ---- mab0: split K/V-projecting attention + cross-block merge ----
    attn_split<4><<<dim3(32, 8), 512, 0, stream>>>(
        q_all + l * 16384, xb, wk, ibk + s0 * 256, wv, ibv + s0 * 256, pmask,
        Opart, Mpart, Lpart);
    attn_merge<4><<<dim3(32, 8), 256, 0, stream>>>(
        q_all + l * 16384, Opart, Mpart, Lpart, ob);
    ln4<<<512, 256, 0, stream>>>(ob, ob, ig0 + s0 * 256, ib0 + s0 * 256);
    gemm_bp<3, false, 256><<<16, 512, 0, stream>>>(
        ob, wo0, wo0, wo0, ibo + s0 * 256, ibo + s0 * 256, ibo + s0 * 256,
        hb, hb, hb, ig1 + s0 * 256, ib1 + s0 * 256, 1, 1);
    // ---- mab1 K,V (consume hb, tiny) ----
    gemm_bp<0, false, 128><<<64, 256, 0, stream>>>(
        hb, wk1, wv1, wv1, ibk + s1 * 256, ibv + s1 * 256, ibv + s1 * 256,
        kbw, vbw, vbw, nullptr, nullptr, 2, 4);
    // ---- mab1 fused: q-proj + attention + LN0 + Wo + LN1, xb in-place ----
    mab1_fused<<<dim3(32, 32), 512, 0, stream>>>(
        xb, wq1, ibq + s1 * 256, kbw, vbw, wo1, ibo + s1 * 256,
        ig0 + s1 * 256, ib0 + s1 * 256, ig1 + s1 * 256, ib1 + s1 * 256, xb);
  }
  // ---- PMA: split K/V-projecting attention + merge ----
  attn_split<2><<<dim3(32, 8), 512, 0, stream>>>(
      q_all + 49152, xb, wt + (size_t)25 * 65536, pbk, wt + (size_t)26 * 65536, pbv, pmask,
      Opart, Mpart, Lpart);
  attn_merge<2><<<dim3(32, 8), 256, 0, stream>>>(
      q_all + 49152, Opart, Mpart, Lpart, ob);
  ln4<<<256, 256, 0, stream>>>(ob, ob, pg0, pb0);
  gemm_bp<3, true, 256><<<8, 512, 0, stream>>>(
      ob, wt + (size_t)27 * 65536, wt + (size_t)27 * 65536, wt + (size_t)27 * 65536,
      pbo, pbo, pbo, d_out, d_out, d_out, pg1, pb1, 1, 1);
}

// Round 16
// 803.743 us; speedup vs baseline: 1.0131x; 1.0131x over previous
//
#include <hip/hip_runtime.h>
#include <hip/hip_bf16.h>

// SetTransformer encoder forward. B=32,N=2048,D=256,H=8,dh=32,NI=64,NL=3,NS=32.
// Round 16: revert to r14 structure (793us, best). One change: attn_fused chunk loop
// is phase-staggered by head ((c+h)&3) so the 8 xb-sharing blocks of a batch don't
// miss the same L2 lines in lockstep (8-way concurrent miss -> 2-way; FETCH 115->~55MB).
// Online softmax is order-invariant up to f32 rounding -> absmax unchanged.

typedef __attribute__((ext_vector_type(8))) short short8;
typedef __attribute__((ext_vector_type(4))) float f32x4;
typedef __attribute__((ext_vector_type(4))) ushort ushort4v;

__device__ __forceinline__ ushort f2bf(float f) {
  uint u = __builtin_bit_cast(uint, f);
  u += 0x7fffu + ((u >> 16) & 1u);
  return (ushort)(u >> 16);
}
__device__ __forceinline__ float bf2f(ushort h) {
  uint u = (uint)h << 16;
  return __builtin_bit_cast(float, u);
}

// ---------------- weight prep: transpose 256x256 f32 [k][n] -> bf16 [n][k] ----------------
__global__ __launch_bounds__(256) void prep_weights(
    const float* __restrict__ Wq, const float* __restrict__ Wk,
    const float* __restrict__ Wv, const float* __restrict__ Wo,
    const float* __restrict__ pWq, const float* __restrict__ pWk,
    const float* __restrict__ pWv, const float* __restrict__ pWo,
    ushort* __restrict__ wt)
{
  __shared__ float tile[64][65];
  const int m = blockIdx.y;          // 0..27
  const int t = blockIdx.x;          // 0..15
  const int tr = (t >> 2) * 64;      // k block
  const int tc = (t & 3) * 64;       // n block
  const float* src;
  if (m < 24) {
    int l = m >> 3, s = (m >> 2) & 1, w = m & 3;
    const float* base = (w == 0) ? Wq : (w == 1) ? Wk : (w == 2) ? Wv : Wo;
    src = base + (size_t)(l * 2 + s) * 65536;
  } else {
    int w = m & 3;
    src = (w == 0) ? pWq : (w == 1) ? pWk : (w == 2) ? pWv : pWo;
  }
  const int tid = threadIdx.x;
  const int cn = tid & 63;
  const int rk = tid >> 6;
#pragma unroll
  for (int j = 0; j < 16; ++j) {
    int kl = rk + j * 4;
    tile[kl][cn] = src[(size_t)(tr + kl) * 256 + tc + cn];
  }
  __syncthreads();
  ushort* dst = wt + (size_t)m * 65536;
#pragma unroll
  for (int j = 0; j < 16; ++j) {
    int nl = rk + j * 4;
    dst[(size_t)(tc + nl) * 256 + tr + cn] = f2bf(tile[cn][nl]);
  }
}

// ---------------- input projection + exact gelu -> bf16, 8 rows/block ----------------
__global__ __launch_bounds__(256) void proj_gelu(
    const float* __restrict__ xv, const float* __restrict__ yt,
    const float* __restrict__ pW, const float* __restrict__ pb,
    ushort* __restrict__ xb)
{
  const int d = threadIdx.x;
  const int row0 = blockIdx.x * 8;
  const float w0 = pW[d], w1 = pW[256 + d], w2 = pW[512 + d], w3 = pW[768 + d];
  const float bz = pb[d];
#pragma unroll
  for (int rr = 0; rr < 8; ++rr) {
    int row = row0 + rr;
    float f0 = xv[(size_t)row * 3 + 0];
    float f1 = xv[(size_t)row * 3 + 1];
    float f2 = xv[(size_t)row * 3 + 2];
    float f3 = yt[row];
    float a = bz + f0 * w0 + f1 * w1 + f2 * w2 + f3 * w3;
    float g = 0.5f * a * (1.f + erff(a * 0.70710678118654752f));
    xb[(size_t)row * 256 + d] = f2bf(g);
  }
}

// ---------------- batched tiny q-projections (f32 A, M=64/32) ----------------
__global__ __launch_bounds__(256) void gemm_q(
    const float* __restrict__ iI, const float* __restrict__ pS,
    const ushort* __restrict__ wt, const float* __restrict__ ibq,
    const float* __restrict__ pbq, ushort* __restrict__ q_all)
{
  const int bq = blockIdx.x;
  const float* A; const ushort* Wt; const float* bias; ushort* out; int M;
  if (bq < 3) { A = iI + bq * 16384; Wt = wt + (size_t)(bq * 8) * 65536; bias = ibq + bq * 512; out = q_all + bq * 16384; M = 64; }
  else        { A = pS; Wt = wt + (size_t)24 * 65536; bias = pbq; out = q_all + 49152; M = 32; }
  const int tid = threadIdx.x;
  const int wave = tid >> 6, lane = tid & 63;
  const int l15 = lane & 15, l4 = lane >> 4, koff = l4 * 8;
  f32x4 acc[4][4];
#pragma unroll
  for (int i = 0; i < 4; ++i)
#pragma unroll
    for (int j = 0; j < 4; ++j) acc[i][j] = (f32x4)0.f;
#pragma unroll
  for (int ks = 0; ks < 8; ++ks) {
    short8 af[4];
#pragma unroll
    for (int mf = 0; mf < 4; ++mf) {
      if (mf * 16 < M) {
        const float* ap = A + (size_t)(mf * 16 + l15) * 256 + ks * 32 + koff;
        float4 f0 = *(const float4*)ap;
        float4 f1 = *(const float4*)(ap + 4);
        short8 sv;
        sv[0] = (short)f2bf(f0.x); sv[1] = (short)f2bf(f0.y);
        sv[2] = (short)f2bf(f0.z); sv[3] = (short)f2bf(f0.w);
        sv[4] = (short)f2bf(f1.x); sv[5] = (short)f2bf(f1.y);
        sv[6] = (short)f2bf(f1.z); sv[7] = (short)f2bf(f1.w);
        af[mf] = sv;
      } else af[mf] = (short8)0;
    }
#pragma unroll
    for (int nf = 0; nf < 4; ++nf) {
      short8 bf = *(const short8*)(Wt + (size_t)(wave * 64 + nf * 16 + l15) * 256 + ks * 32 + koff);
#pragma unroll
      for (int mf = 0; mf < 4; ++mf)
        acc[mf][nf] = __builtin_amdgcn_mfma_f32_16x16x32_bf16(af[mf], bf, acc[mf][nf], 0, 0, 0);
    }
  }
#pragma unroll
  for (int mf = 0; mf < 4; ++mf) {
    if (mf * 16 >= M) continue;
#pragma unroll
    for (int nf = 0; nf < 4; ++nf) {
      int col = wave * 64 + nf * 16 + l15;
      float bcol = bias[col];
#pragma unroll
      for (int r = 0; r < 4; ++r)
        out[(size_t)(mf * 16 + l4 * 4 + r) * 256 + col] = f2bf(acc[mf][nf][r] + bcol);
    }
  }
}

// ---------------- B-panel GEMM: out = epi(A @ W + bias) ----------------
// 1-D grid with XCD-colocating decode: bid = (x&7) + 8*(yz + nyz*(x>>3)).
template <int EPI, bool OUTF32, int COLS>
__global__ __launch_bounds__(COLS * 2, (COLS == 128) ? 4 : 2) void gemm_bp(
    const ushort* __restrict__ A,
    const ushort* __restrict__ Wt0, const ushort* __restrict__ Wt1, const ushort* __restrict__ Wt2,
    const float* __restrict__ b0, const float* __restrict__ b1, const float* __restrict__ b2,
    void* __restrict__ o0, void* __restrict__ o1, void* __restrict__ o2,
    const float* __restrict__ lng, const float* __restrict__ lnb,
    int ny, int nyz)
{
  constexpr int WC = COLS / 64;
  constexpr int PS = COLS * 64;
  constexpr int ROWB = COLS * 2;
  __shared__ __align__(16) char Bs[4 * PS];
  __shared__ float redbuf[(EPI == 3) ? 1280 : 4];
  const int bid = blockIdx.x;
  const int rest = bid >> 3;
  const int yz = rest % nyz;
  const int bx = ((rest / nyz) << 3) | (bid & 7);
  const int y = yz % ny;
  const int z = yz / ny;
  const ushort* Wt = (z == 0) ? Wt0 : ((z == 1) ? Wt1 : Wt2);
  const float* bias = (z == 0) ? b0 : ((z == 1) ? b1 : b2);
  void* outp = (z == 0) ? o0 : ((z == 1) ? o1 : o2);
  const int pcol = y * COLS;

  const int tid = threadIdx.x;
  const int wave = tid >> 6, lane = tid & 63;
  const int wc = wave % WC, wr = wave / WC;
  const int l15 = lane & 15, l4 = lane >> 4;
  const int row0 = bx * 128;
  const int sn = tid >> 1, sseg = tid & 1;

  f32x4 acc[4][4];
#pragma unroll
  for (int i = 0; i < 4; ++i)
#pragma unroll
    for (int j = 0; j < 4; ++j) acc[i][j] = (f32x4)0.f;

#pragma unroll
  for (int half = 0; half < 2; ++half) {
    if (half) __syncthreads();
    {
      const ushort* src = Wt + (size_t)(pcol + sn) * 256 + half * 128 + sseg * 64;
#pragma unroll
      for (int c = 0; c < 8; ++c) {
        uint4 w = *(const uint4*)(src + c * 8);
        int plane = sseg * 2 + (c >> 2);
        char* dst = Bs + plane * PS + sn * 64 + (((c & 3) * 16) ^ (((sn >> 1) & 3) << 4));
        *(uint4*)dst = w;
      }
    }
    __syncthreads();
#pragma unroll
    for (int ks = 0; ks < 4; ++ks) {
      short8 af[4];
#pragma unroll
      for (int mfa = 0; mfa < 4; ++mfa)
        af[mfa] = *(const short8*)(A + (size_t)(row0 + wr * 64 + mfa * 16 + l15) * 256 + half * 128 + ks * 32 + l4 * 8);
#pragma unroll
      for (int nfb = 0; nfb < 4; ++nfb) {
        int n = wc * 64 + nfb * 16 + l15;
        short8 bf = *(const short8*)(Bs + ks * PS + n * 64 + ((l4 * 16) ^ (((n >> 1) & 3) << 4)));
#pragma unroll
        for (int mfa = 0; mfa < 4; ++mfa)
          acc[mfa][nfb] = __builtin_amdgcn_mfma_f32_16x16x32_bf16(bf, af[mfa], acc[mfa][nfb], 0, 0, 0);
      }
    }
  }

  if constexpr (EPI == 0) {
    __syncthreads();
#pragma unroll
    for (int nfb = 0; nfb < 4; ++nfb) {
      f32x4 bv = *(const f32x4*)(bias + pcol + wc * 64 + nfb * 16 + l4 * 4);
      int colb = wc * 128 + nfb * 32 + l4 * 8;
#pragma unroll
      for (int mfa = 0; mfa < 4; ++mfa) {
        int row = wr * 64 + mfa * 16 + l15;
        ushort4v pk;
#pragma unroll
        for (int i = 0; i < 4; ++i) pk[i] = f2bf(acc[mfa][nfb][i] + bv[i]);
        *(ushort4v*)(Bs + row * ROWB + (colb ^ ((row & 7) << 4))) = pk;
      }
    }
    __syncthreads();
    const int srow = tid >> 2, seg = tid & 3;
#pragma unroll
    for (int rr = 0; rr < 2; ++rr) {
      int row = srow + rr * 64;
      int x = (row & 7) << 4;
      ushort* gdst = (ushort*)outp + (size_t)(row0 + row) * 256 + pcol;
#pragma unroll
      for (int it = 0; it < 4; ++it) {
        int colb = seg * 16 + it * 64;
        uint4 v = *(const uint4*)(Bs + row * ROWB + (colb ^ x));
        *(uint4*)(gdst + colb / 2) = v;
      }
    }
  } else {
    float* red1 = redbuf;
    float* red2 = redbuf + 512;
    float* mv_ = redbuf + 1024;
    float* rv_ = redbuf + 1152;
    float s1[4] = {0.f, 0.f, 0.f, 0.f}, s2[4] = {0.f, 0.f, 0.f, 0.f};
#pragma unroll
    for (int nfb = 0; nfb < 4; ++nfb) {
      int col0 = wc * 64 + nfb * 16 + l4 * 4;
      f32x4 bv = *(const f32x4*)(bias + col0);
#pragma unroll
      for (int mfa = 0; mfa < 4; ++mfa) {
        size_t row = (size_t)row0 + wr * 64 + mfa * 16 + l15;
        ushort4v rz = *(const ushort4v*)(A + row * 256 + col0);
#pragma unroll
        for (int i = 0; i < 4; ++i) {
          float zz = bf2f(rz[i]) + fmaxf(acc[mfa][nfb][i] + bv[i], 0.f);
          acc[mfa][nfb][i] = zz;
          s1[mfa] += zz;
          s2[mfa] += zz * zz;
        }
      }
    }
#pragma unroll
    for (int mfa = 0; mfa < 4; ++mfa) {
      s1[mfa] += __shfl_xor(s1[mfa], 16); s1[mfa] += __shfl_xor(s1[mfa], 32);
      s2[mfa] += __shfl_xor(s2[mfa], 16); s2[mfa] += __shfl_xor(s2[mfa], 32);
    }
    if (l4 == 0) {
#pragma unroll
      for (int mfa = 0; mfa < 4; ++mfa) {
        red1[wc * 128 + wr * 64 + mfa * 16 + l15] = s1[mfa];
        red2[wc * 128 + wr * 64 + mfa * 16 + l15] = s2[mfa];
      }
    }
    __syncthreads();
    if (tid < 128) {
      float m1 = red1[tid] + red1[128 + tid] + red1[256 + tid] + red1[384 + tid];
      float m2 = red2[tid] + red2[128 + tid] + red2[256 + tid] + red2[384 + tid];
      float mean = m1 * 0.00390625f;
      float var = m2 * 0.00390625f - mean * mean;
      mv_[tid] = mean;
      rv_[tid] = rsqrtf(var + 1e-5f);
    }
    __syncthreads();
#pragma unroll
    for (int nfb = 0; nfb < 4; ++nfb) {
      int col0 = wc * 64 + nfb * 16 + l4 * 4;
      f32x4 gg = *(const f32x4*)(lng + col0);
      f32x4 bb = *(const f32x4*)(lnb + col0);
      int colb = col0 * 2;
#pragma unroll
      for (int mfa = 0; mfa < 4; ++mfa) {
        int lr = wr * 64 + mfa * 16 + l15;
        float mean = mv_[lr], rs = rv_[lr];
        if constexpr (OUTF32) {
          f32x4 w;
#pragma unroll
          for (int i = 0; i < 4; ++i) w[i] = (acc[mfa][nfb][i] - mean) * rs * gg[i] + bb[i];
          *(f32x4*)((float*)outp + ((size_t)row0 + lr) * 256 + col0) = w;
        } else {
          ushort4v pk;
#pragma unroll
          for (int i = 0; i < 4; ++i) pk[i] = f2bf((acc[mfa][nfb][i] - mean) * rs * gg[i] + bb[i]);
          *(ushort4v*)(Bs + lr * ROWB + (colb ^ ((lr & 7) << 4))) = pk;
        }
      }
    }
    if constexpr (!OUTF32) {
      __syncthreads();
      const int srow = tid >> 2, seg = tid & 3;
      int x = (srow & 7) << 4;
      ushort* gdst = (ushort*)outp + (size_t)(row0 + srow) * 256;
#pragma unroll
      for (int it = 0; it < 8; ++it) {
        int colb = seg * 16 + it * 64;
        uint4 v = *(const uint4*)(Bs + srow * ROWB + (colb ^ x));
        *(uint4*)(gdst + colb / 2) = v;
      }
    }
  }
}

// ---------------- attn_fused: on-the-fly K/V projection + flash attention ----------------
// nq small (64/32), nk=2048, masked, q shared across batch. grid(b=32, h=8): the 8
// head-blocks of a batch share one XCD L2 (bid % 8 == b % 8). Chunk loop is phase-
// staggered by head ((c+h)&3) so sharers don't miss the same xb lines in lockstep.
template <int MF>
__global__ __launch_bounds__(512) void attn_fused(
    const ushort* __restrict__ qb, const ushort* __restrict__ xbuf,
    const ushort* __restrict__ wk, const float* __restrict__ bk,
    const ushort* __restrict__ wv, const float* __restrict__ bv,
    const float* __restrict__ mask, ushort* __restrict__ O)
{
  __shared__ __align__(16) ushort Ps[8][64][72];   // 72KB; merge overlay at end
  __shared__ __align__(16) ushort Vt[8][32][72];   // 36KB
  __shared__ __align__(16) ushort Kc[8][64][40];   // 40KB: projected K chunk
  const int b = blockIdx.x, h = blockIdx.y;
  const int tid = threadIdx.x;
  const int w = tid >> 6, lane = tid & 63;
  const int l15 = lane & 15, l4 = lane >> 4;
  const int koff = l4 * 8;
  const int kvbase = b * 2048;

  short8 qf[MF];
#pragma unroll
  for (int mf = 0; mf < MF; ++mf)
    qf[mf] = *(const short8*)(qb + (size_t)(mf * 16 + l15) * 256 + h * 32 + koff);

  f32x4 bkv[2], bvv[2];
#pragma unroll
  for (int nfb = 0; nfb < 2; ++nfb) {
    bkv[nfb] = *(const f32x4*)(bk + h * 32 + nfb * 16 + l4 * 4);
    bvv[nfb] = *(const f32x4*)(bv + h * 32 + nfb * 16 + l4 * 4);
  }

  f32x4 Oa[MF][2];
  float Mr[MF][4], Lr[MF][4];
#pragma unroll
  for (int mf = 0; mf < MF; ++mf) {
    Oa[mf][0] = (f32x4)0.f; Oa[mf][1] = (f32x4)0.f;
#pragma unroll
    for (int r = 0; r < 4; ++r) { Mr[mf][r] = -1e30f; Lr[mf][r] = 0.f; }
  }

  for (int cc = 0; cc < 4; ++cc) {
    const int c = (cc + h) & 3;  // head-phase stagger: sharers touch different chunks
    const int kc = w * 256 + c * 64;
    // ---- project K,V for this 64-key chunk (swapped MFMA: lane=(key l15, col l4*4+i)) ----
    f32x4 ak[4][2], av[4][2];
#pragma unroll
    for (int i = 0; i < 4; ++i) {
      ak[i][0] = (f32x4)0.f; ak[i][1] = (f32x4)0.f;
      av[i][0] = (f32x4)0.f; av[i][1] = (f32x4)0.f;
    }
#pragma unroll
    for (int ks = 0; ks < 8; ++ks) {
      short8 af[4];
#pragma unroll
      for (int mfa = 0; mfa < 4; ++mfa)
        af[mfa] = *(const short8*)(xbuf + (size_t)(kvbase + kc + mfa * 16 + l15) * 256 + ks * 32 + koff);
#pragma unroll
      for (int nfb = 0; nfb < 2; ++nfb) {
        int n = h * 32 + nfb * 16 + l15;
        short8 wkf = *(const short8*)(wk + (size_t)n * 256 + ks * 32 + koff);
        short8 wvf = *(const short8*)(wv + (size_t)n * 256 + ks * 32 + koff);
#pragma unroll
        for (int mfa = 0; mfa < 4; ++mfa) {
          ak[mfa][nfb] = __builtin_amdgcn_mfma_f32_16x16x32_bf16(wkf, af[mfa], ak[mfa][nfb], 0, 0, 0);
          av[mfa][nfb] = __builtin_amdgcn_mfma_f32_16x16x32_bf16(wvf, af[mfa], av[mfa][nfb], 0, 0, 0);
        }
      }
    }
    // stage K chunk: Kc[key][col] bf16 (+bias) — wave-private, in-order
#pragma unroll
    for (int nfb = 0; nfb < 2; ++nfb)
#pragma unroll
      for (int mfa = 0; mfa < 4; ++mfa) {
        ushort4v pk;
#pragma unroll
        for (int i = 0; i < 4; ++i) pk[i] = f2bf(ak[mfa][nfb][i] + bkv[nfb][i]);
        *(ushort4v*)&Kc[w][mfa * 16 + l15][nfb * 16 + l4 * 4] = pk;
      }
    // stage V^T: Vt[col][key] bf16 (+bias)
#pragma unroll
    for (int nfb = 0; nfb < 2; ++nfb)
#pragma unroll
      for (int mfa = 0; mfa < 4; ++mfa)
#pragma unroll
        for (int i = 0; i < 4; ++i)
          Vt[w][nfb * 16 + l4 * 4 + i][mfa * 16 + l15] = f2bf(av[mfa][nfb][i] + bvv[nfb][i]);

    // ---- S = (Q K^T)/16 + mask ----
    f32x4 S[MF][4];
#pragma unroll
    for (int nf = 0; nf < 4; ++nf) {
      short8 kf = *(const short8*)&Kc[w][nf * 16 + l15][koff];
#pragma unroll
      for (int mf = 0; mf < MF; ++mf)
        S[mf][nf] = __builtin_amdgcn_mfma_f32_16x16x32_bf16(qf[mf], kf, (f32x4)0.f, 0, 0, 0);
    }
    float mv[4];
#pragma unroll
    for (int nf = 0; nf < 4; ++nf)
      mv[nf] = mask[(size_t)b * 2048 + kc + nf * 16 + l15];
#pragma unroll
    for (int mf = 0; mf < MF; ++mf)
#pragma unroll
      for (int nf = 0; nf < 4; ++nf)
#pragma unroll
        for (int r = 0; r < 4; ++r) {
          float s = S[mf][nf][r] * 0.0625f;
          S[mf][nf][r] = (mv[nf] != 0.f) ? s : -1e4f;
        }
#pragma unroll
    for (int mf = 0; mf < MF; ++mf)
#pragma unroll
      for (int r = 0; r < 4; ++r) {
        float pm = fmaxf(fmaxf(S[mf][0][r], S[mf][1][r]), fmaxf(S[mf][2][r], S[mf][3][r]));
        pm = fmaxf(pm, __shfl_xor(pm, 1));
        pm = fmaxf(pm, __shfl_xor(pm, 2));
        pm = fmaxf(pm, __shfl_xor(pm, 4));
        pm = fmaxf(pm, __shfl_xor(pm, 8));
        float Mnew = fmaxf(Mr[mf][r], pm);
        float corr = __expf(Mr[mf][r] - Mnew);
        Mr[mf][r] = Mnew;
        float rs = 0.f;
#pragma unroll
        for (int nf = 0; nf < 4; ++nf) {
          float p = __expf(S[mf][nf][r] - Mnew);
          S[mf][nf][r] = p;
          rs += p;
        }
        rs += __shfl_xor(rs, 1);
        rs += __shfl_xor(rs, 2);
        rs += __shfl_xor(rs, 4);
        rs += __shfl_xor(rs, 8);
        Lr[mf][r] = Lr[mf][r] * corr + rs;
        Oa[mf][0][r] *= corr;
        Oa[mf][1][r] *= corr;
      }
#pragma unroll
    for (int mf = 0; mf < MF; ++mf)
#pragma unroll
      for (int nf = 0; nf < 4; ++nf)
#pragma unroll
        for (int r = 0; r < 4; ++r)
          Ps[w][mf * 16 + l4 * 4 + r][nf * 16 + l15] = f2bf(S[mf][nf][r]);
#pragma unroll
    for (int ks = 0; ks < 2; ++ks) {
      short8 pf[MF];
#pragma unroll
      for (int mf = 0; mf < MF; ++mf)
        pf[mf] = *(const short8*)&Ps[w][mf * 16 + l15][ks * 32 + koff];
#pragma unroll
      for (int nf2 = 0; nf2 < 2; ++nf2) {
        short8 vf = *(const short8*)&Vt[w][nf2 * 16 + l15][ks * 32 + koff];
#pragma unroll
        for (int mf = 0; mf < MF; ++mf)
          Oa[mf][nf2] = __builtin_amdgcn_mfma_f32_16x16x32_bf16(pf[mf], vf, Oa[mf][nf2], 0, 0, 0);
      }
    }
  }

  // ---- merge 8 partials via LDS (overlay on Ps) ----
  __syncthreads();
  float* Mw = (float*)&Ps[0][0][0];
  float* Lw = Mw + 512;
  float* Ow = Lw + 512;  // [8][64][33]
#pragma unroll
  for (int mf = 0; mf < MF; ++mf)
#pragma unroll
    for (int r = 0; r < 4; ++r) {
      int row = mf * 16 + l4 * 4 + r;
      if (l15 == 0) { Mw[w * 64 + row] = Mr[mf][r]; Lw[w * 64 + row] = Lr[mf][r]; }
#pragma unroll
      for (int nf2 = 0; nf2 < 2; ++nf2)
        Ow[(w * 64 + row) * 33 + nf2 * 16 + l15] = Oa[mf][nf2][r];
    }
  __syncthreads();
  const int NQ = MF * 16;
  int row = tid >> 3, dg = tid & 7;
  if (row < NQ) {
    float mm = -1e30f;
#pragma unroll
    for (int s = 0; s < 8; ++s) mm = fmaxf(mm, Mw[s * 64 + row]);
    float den = 0.f, es[8];
#pragma unroll
    for (int s = 0; s < 8; ++s) {
      es[s] = __expf(Mw[s * 64 + row] - mm);
      den += Lw[s * 64 + row] * es[s];
    }
    float invden = 1.f / den;
    ushort4v pk;
#pragma unroll
    for (int i = 0; i < 4; ++i) {
      int d = dg * 4 + i;
      float num = 0.f;
#pragma unroll
      for (int s = 0; s < 8; ++s) num += Ow[(s * 64 + row) * 33 + d] * es[s];
      float qv = bf2f(qb[(size_t)row * 256 + h * 32 + d]);
      pk[i] = f2bf(qv + num * invden);
    }
    *(ushort4v*)(O + (size_t)(b * NQ + row) * 256 + h * 32 + dg * 4) = pk;
  }
}

// ---------------- mab1_fused (r10 config): q-proj + attention(nk=64) + LN0 + Wo + LN1 ----
// grid(qt=32, b=32), block 512 = 8 waves = 8 heads over the same 64 q-rows.
__global__ __launch_bounds__(512, 4) void mab1_fused(
    const ushort* __restrict__ xb, const ushort* __restrict__ wq,
    const float* __restrict__ bq,
    const ushort* __restrict__ kb, const ushort* __restrict__ vb,
    const ushort* __restrict__ wo, const float* __restrict__ bo,
    const float* __restrict__ g0, const float* __restrict__ b0v,
    const float* __restrict__ g1, const float* __restrict__ b1v,
    ushort* __restrict__ outb)
{
  __shared__ __align__(16) ushort Qs[8][64][40];   // 40KB q tiles; later o_s[64][264]
  __shared__ __align__(16) ushort Psh[8][16][40];  // 10KB P half-tile (per-mf staging)
  __shared__ __align__(16) ushort Vth[8][32][40];  // 20KB V^T half (32 keys)
  __shared__ float red1[8][64], red2[8][64], mv_[64], rv_[64];
  ushort* o_s = &Qs[0][0][0];
  constexpr int OS = 264;

  const int qt = blockIdx.x, b = blockIdx.y;
  const int tid = threadIdx.x;
  const int w = tid >> 6, lane = tid & 63;
  const int l15 = lane & 15, l4 = lane >> 4;
  const int koff = l4 * 8;
  const size_t row0 = (size_t)b * 2048 + qt * 64;
  const int kvbase = b * 64;
  const int h = w;

  short8 kf[4];
#pragma unroll
  for (int nf = 0; nf < 4; ++nf)
    kf[nf] = *(const short8*)(kb + (size_t)(kvbase + nf * 16 + l15) * 256 + h * 32 + koff);
  const int key = lane & 31, dh2 = lane >> 5;
  short8 vvB0, vvB1;
  {
    const ushort* vsrcA = vb + (size_t)(kvbase + key) * 256 + h * 32 + dh2 * 16;
    const ushort* vsrcB = vb + (size_t)(kvbase + 32 + key) * 256 + h * 32 + dh2 * 16;
    short8 vvA0 = *(const short8*)vsrcA;
    short8 vvA1 = *(const short8*)(vsrcA + 8);
    vvB0 = *(const short8*)vsrcB;
    vvB1 = *(const short8*)(vsrcB + 8);
#pragma unroll
    for (int j = 0; j < 8; ++j) Vth[w][dh2 * 16 + j][key] = (ushort)vvA0[j];
#pragma unroll
    for (int j = 0; j < 8; ++j) Vth[w][dh2 * 16 + 8 + j][key] = (ushort)vvA1[j];
  }

  {
    f32x4 qa[4][2];
#pragma unroll
    for (int i = 0; i < 4; ++i) { qa[i][0] = (f32x4)0.f; qa[i][1] = (f32x4)0.f; }
#pragma unroll
    for (int ks = 0; ks < 8; ++ks) {
      short8 af[4];
#pragma unroll
      for (int mfa = 0; mfa < 4; ++mfa)
        af[mfa] = *(const short8*)(xb + (row0 + mfa * 16 + l15) * 256 + ks * 32 + koff);
#pragma unroll
      for (int nfb = 0; nfb < 2; ++nfb) {
        int n = w * 32 + nfb * 16 + l15;
        short8 bf = *(const short8*)(wq + (size_t)n * 256 + ks * 32 + koff);
#pragma unroll
        for (int mfa = 0; mfa < 4; ++mfa)
          qa[mfa][nfb] = __builtin_amdgcn_mfma_f32_16x16x32_bf16(bf, af[mfa], qa[mfa][nfb], 0, 0, 0);
      }
    }
#pragma unroll
    for (int nfb = 0; nfb < 2; ++nfb) {
      f32x4 bvq = *(const f32x4*)(bq + w * 32 + nfb * 16 + l4 * 4);
#pragma unroll
      for (int mfa = 0; mfa < 4; ++mfa) {
        ushort4v pk;
#pragma unroll
        for (int i = 0; i < 4; ++i) pk[i] = f2bf(qa[mfa][nfb][i] + bvq[i]);
        *(ushort4v*)&Qs[w][mfa * 16 + l15][nfb * 16 + l4 * 4] = pk;
      }
    }
  }

  short8 qf[4];
#pragma unroll
  for (int mf = 0; mf < 4; ++mf)
    qf[mf] = *(const short8*)&Qs[w][mf * 16 + l15][koff];

  f32x4 S[4][4];
#pragma unroll
  for (int nf = 0; nf < 4; ++nf) {
#pragma unroll
    for (int mf = 0; mf < 4; ++mf)
      S[mf][nf] = __builtin_amdgcn_mfma_f32_16x16x32_bf16(qf[mf], kf[nf], (f32x4)0.f, 0, 0, 0);
  }
  float Lr[4][4];
#pragma unroll
  for (int mf = 0; mf < 4; ++mf)
#pragma unroll
    for (int r = 0; r < 4; ++r) {
      float pm = fmaxf(fmaxf(S[mf][0][r], S[mf][1][r]), fmaxf(S[mf][2][r], S[mf][3][r])) * 0.0625f;
      pm = fmaxf(pm, __shfl_xor(pm, 1));
      pm = fmaxf(pm, __shfl_xor(pm, 2));
      pm = fmaxf(pm, __shfl_xor(pm, 4));
      pm = fmaxf(pm, __shfl_xor(pm, 8));
      float rs = 0.f;
#pragma unroll
      for (int nf = 0; nf < 4; ++nf) {
        float pp = __expf(S[mf][nf][r] * 0.0625f - pm);
        S[mf][nf][r] = pp;
        rs += pp;
      }
      rs += __shfl_xor(rs, 1);
      rs += __shfl_xor(rs, 2);
      rs += __shfl_xor(rs, 4);
      rs += __shfl_xor(rs, 8);
      Lr[mf][r] = rs;
    }

  f32x4 Oa[4][2];
#pragma unroll
  for (int mf = 0; mf < 4; ++mf) { Oa[mf][0] = (f32x4)0.f; Oa[mf][1] = (f32x4)0.f; }
#pragma unroll
  for (int mf = 0; mf < 4; ++mf) {
#pragma unroll
    for (int nf = 0; nf < 2; ++nf)
#pragma unroll
      for (int r = 0; r < 4; ++r)
        Psh[w][l4 * 4 + r][nf * 16 + l15] = f2bf(S[mf][nf][r]);
    short8 pf = *(const short8*)&Psh[w][l15][koff];
#pragma unroll
    for (int nf2 = 0; nf2 < 2; ++nf2) {
      short8 vf = *(const short8*)&Vth[w][nf2 * 16 + l15][koff];
      Oa[mf][nf2] = __builtin_amdgcn_mfma_f32_16x16x32_bf16(pf, vf, Oa[mf][nf2], 0, 0, 0);
    }
  }
#pragma unroll
  for (int j = 0; j < 8; ++j) Vth[w][dh2 * 16 + j][key] = (ushort)vvB0[j];
#pragma unroll
  for (int j = 0; j < 8; ++j) Vth[w][dh2 * 16 + 8 + j][key] = (ushort)vvB1[j];
#pragma unroll
  for (int mf = 0; mf < 4; ++mf) {
#pragma unroll
    for (int nf = 0; nf < 2; ++nf)
#pragma unroll
      for (int r = 0; r < 4; ++r)
        Psh[w][l4 * 4 + r][nf * 16 + l15] = f2bf(S[mf][nf + 2][r]);
    short8 pf = *(const short8*)&Psh[w][l15][koff];
#pragma unroll
    for (int nf2 = 0; nf2 < 2; ++nf2) {
      short8 vf = *(const short8*)&Vth[w][nf2 * 16 + l15][koff];
      Oa[mf][nf2] = __builtin_amdgcn_mfma_f32_16x16x32_bf16(pf, vf, Oa[mf][nf2], 0, 0, 0);
    }
  }

  {
    float s1[4][4], s2[4][4];
#pragma unroll
    for (int mf = 0; mf < 4; ++mf)
#pragma unroll
      for (int r = 0; r < 4; ++r) {
        float invL = 1.f / Lr[mf][r];
        s1[mf][r] = 0.f; s2[mf][r] = 0.f;
#pragma unroll
        for (int nf2 = 0; nf2 < 2; ++nf2) {
          float qv = bf2f(Qs[w][mf * 16 + l4 * 4 + r][nf2 * 16 + l15]);
          float z = qv + Oa[mf][nf2][r] * invL;
          Oa[mf][nf2][r] = z;
          s1[mf][r] += z;
          s2[mf][r] += z * z;
        }
#pragma unroll
        for (int off = 1; off < 16; off <<= 1) {
          s1[mf][r] += __shfl_xor(s1[mf][r], off);
          s2[mf][r] += __shfl_xor(s2[mf][r], off);
        }
        if (l15 == 0) {
          int row = mf * 16 + l4 * 4 + r;
          red1[w][row] = s1[mf][r];
          red2[w][row] = s2[mf][r];
        }
      }
  }
  __syncthreads();
  if (tid < 64) {
    float m1 = 0.f, m2 = 0.f;
#pragma unroll
    for (int s = 0; s < 8; ++s) { m1 += red1[s][tid]; m2 += red2[s][tid]; }
    float mean = m1 * 0.00390625f;
    float var = m2 * 0.00390625f - mean * mean;
    mv_[tid] = mean;
    rv_[tid] = rsqrtf(var + 1e-5f);
  }
  __syncthreads();
#pragma unroll
  for (int nf2 = 0; nf2 < 2; ++nf2) {
    int col = h * 32 + nf2 * 16 + l15;
    float gc = g0[col], bc = b0v[col];
#pragma unroll
    for (int mf = 0; mf < 4; ++mf)
#pragma unroll
      for (int r = 0; r < 4; ++r) {
        int row = mf * 16 + l4 * 4 + r;
        float v = (Oa[mf][nf2][r] - mv_[row]) * rv_[row] * gc + bc;
        o_s[row * OS + col] = f2bf(v);
      }
  }
  __syncthreads();

  f32x4 oa[4][2];
#pragma unroll
  for (int i = 0; i < 4; ++i) { oa[i][0] = (f32x4)0.f; oa[i][1] = (f32x4)0.f; }
#pragma unroll
  for (int ks = 0; ks < 8; ++ks) {
    short8 af[4];
#pragma unroll
    for (int mfa = 0; mfa < 4; ++mfa)
      af[mfa] = *(const short8*)&o_s[(mfa * 16 + l15) * OS + ks * 32 + koff];
#pragma unroll
    for (int nfb = 0; nfb < 2; ++nfb) {
      int n = w * 32 + nfb * 16 + l15;
      short8 bf = *(const short8*)(wo + (size_t)n * 256 + ks * 32 + koff);
#pragma unroll
      for (int mfa = 0; mfa < 4; ++mfa)
        oa[mfa][nfb] = __builtin_amdgcn_mfma_f32_16x16x32_bf16(bf, af[mfa], oa[mfa][nfb], 0, 0, 0);
    }
  }
  float t1[4] = {0.f, 0.f, 0.f, 0.f}, t2[4] = {0.f, 0.f, 0.f, 0.f};
#pragma unroll
  for (int nfb = 0; nfb < 2; ++nfb) {
    int col0 = w * 32 + nfb * 16 + l4 * 4;
    f32x4 bvo = *(const f32x4*)(bo + col0);
#pragma unroll
    for (int mfa = 0; mfa < 4; ++mfa) {
      int row = mfa * 16 + l15;
      ushort4v rz = *(const ushort4v*)&o_s[row * OS + col0];
#pragma unroll
      for (int i = 0; i < 4; ++i) {
        float zz = bf2f(rz[i]) + fmaxf(oa[mfa][nfb][i] + bvo[i], 0.f);
        oa[mfa][nfb][i] = zz;
        t1[mfa] += zz;
        t2[mfa] += zz * zz;
      }
    }
  }
#pragma unroll
  for (int mfa = 0; mfa < 4; ++mfa) {
    t1[mfa] += __shfl_xor(t1[mfa], 16); t1[mfa] += __shfl_xor(t1[mfa], 32);
    t2[mfa] += __shfl_xor(t2[mfa], 16); t2[mfa] += __shfl_xor(t2[mfa], 32);
  }
  if (l4 == 0) {
#pragma unroll
    for (int mfa = 0; mfa < 4; ++mfa) {
      red1[w][mfa * 16 + l15] = t1[mfa];
      red2[w][mfa * 16 + l15] = t2[mfa];
    }
  }
  __syncthreads();
  if (tid < 64) {
    float m1 = 0.f, m2 = 0.f;
#pragma unroll
    for (int s = 0; s < 8; ++s) { m1 += red1[s][tid]; m2 += red2[s][tid]; }
    float mean = m1 * 0.00390625f;
    float var = m2 * 0.00390625f - mean * mean;
    mv_[tid] = mean;
    rv_[tid] = rsqrtf(var + 1e-5f);
  }
  __syncthreads();
#pragma unroll
  for (int nfb = 0; nfb < 2; ++nfb) {
    int col0 = w * 32 + nfb * 16 + l4 * 4;
    f32x4 gg = *(const f32x4*)(g1 + col0);
    f32x4 bb = *(const f32x4*)(b1v + col0);
#pragma unroll
    for (int mfa = 0; mfa < 4; ++mfa) {
      int row = mfa * 16 + l15;
      ushort4v pk;
#pragma unroll
      for (int i = 0; i < 4; ++i)
        pk[i] = f2bf((oa[mfa][nfb][i] - mv_[row]) * rv_[row] * gg[i] + bb[i]);
      *(ushort4v*)&o_s[row * OS + col0] = pk;
    }
  }
  __syncthreads();
  {
    const int r_ = tid >> 3, sg = tid & 7;
    ushort* gdst = outb + (row0 + r_) * 256 + sg * 32;
    const ushort* src = &o_s[r_ * OS + sg * 32];
#pragma unroll
    for (int it = 0; it < 4; ++it) {
      uint4 v = *(const uint4*)(src + it * 8);
      *(uint4*)(gdst + it * 8) = v;
    }
  }
}

// ---------------- small LayerNorm: bf16 in/out, wave per row ----------------
__global__ __launch_bounds__(256) void ln4(
    const ushort* __restrict__ in, ushort* __restrict__ out,
    const float* __restrict__ g, const float* __restrict__ bb)
{
  const int w = threadIdx.x >> 6, lane = threadIdx.x & 63;
  const size_t row = (size_t)blockIdx.x * 4 + w;
  ushort4v u = *(const ushort4v*)(in + row * 256 + lane * 4);
  float v[4];
#pragma unroll
  for (int i = 0; i < 4; ++i) v[i] = bf2f(u[i]);
  float s1 = v[0] + v[1] + v[2] + v[3];
  float s2 = v[0] * v[0] + v[1] * v[1] + v[2] * v[2] + v[3] * v[3];
#pragma unroll
  for (int off = 1; off < 64; off <<= 1) {
    s1 += __shfl_xor(s1, off);
    s2 += __shfl_xor(s2, off);
  }
  float mean = s1 * 0.00390625f;
  float var = s2 * 0.00390625f - mean * mean;
  float rs = rsqrtf(var + 1e-5f);
  f32x4 gg = *(const f32x4*)(g + lane * 4);
  f32x4 bv = *(const f32x4*)(bb + lane * 4);
  ushort4v p;
#pragma unroll
  for (int i = 0; i < 4; ++i) p[i] = f2bf((v[i] - mean) * rs * gg[i] + bv[i]);
  *(ushort4v*)(out + row * 256 + lane * 4) = p;
}

extern "C" void kernel_launch(void* const* d_in, const int* in_sizes, int n_in,
                              void* d_out, int out_size, void* d_ws, size_t ws_size,
                              hipStream_t stream) {
  const float* xv = (const float*)d_in[0];
  const float* yt = (const float*)d_in[1];
  const float* pmask = (const float*)d_in[2];
  const float* prW = (const float*)d_in[3];
  const float* prb = (const float*)d_in[4];
  const float* iI = (const float*)d_in[5];
  const float* iWq = (const float*)d_in[6];
  const float* ibq = (const float*)d_in[7];
  const float* iWk = (const float*)d_in[8];
  const float* ibk = (const float*)d_in[9];
  const float* iWv = (const float*)d_in[10];
  const float* ibv = (const float*)d_in[11];
  const float* iWo = (const float*)d_in[12];
  const float* ibo = (const float*)d_in[13];
  const float* ig0 = (const float*)d_in[14];
  const float* ib0 = (const float*)d_in[15];
  const float* ig1 = (const float*)d_in[16];
  const float* ib1 = (const float*)d_in[17];
  const float* pS = (const float*)d_in[18];
  const float* pWq = (const float*)d_in[19];
  const float* pbq = (const float*)d_in[20];
  const float* pWk = (const float*)d_in[21];
  const float* pbk = (const float*)d_in[22];
  const float* pWv = (const float*)d_in[23];
  const float* pbv = (const float*)d_in[24];
  const float* pWo = (const float*)d_in[25];
  const float* pbo = (const float*)d_in[26];
  const float* pg0 = (const float*)d_in[27];
  const float* pb0 = (const float*)d_in[28];
  const float* pg1 = (const float*)d_in[29];
  const float* pb1 = (const float*)d_in[30];

  char* ws = (char*)d_ws;
  if (ws_size < 172621824u) return;
  ushort* xb = (ushort*)(ws + 0);              // 32MB (B*N x 256)
  ushort* ob = (ushort*)(ws + 33554432);       // 32MB (attn/LN scratch)
  ushort* hb = (ushort*)(ws + 67108864);       // 1MB  (B*NI x 256)
  ushort* kbw = (ushort*)(ws + 101711872);     // 32MB (mab1 K)
  ushort* vbw = (ushort*)(ws + 135266304);     // 32MB (mab1 V)
  ushort* wt = (ushort*)(ws + 168820736);      // 3.5MB transposed weights
  ushort* q_all = (ushort*)(ws + 172490752);   // 112KB tiny-q outputs

  prep_weights<<<dim3(16, 28), 256, 0, stream>>>(iWq, iWk, iWv, iWo, pWq, pWk, pWv, pWo, wt);
  proj_gelu<<<8192, 256, 0, stream>>>(xv, yt, prW, prb, xb);
  gemm_q<<<4, 256, 0, stream>>>(iI, pS, wt, ibq, pbq, q_all);

  for (int l = 0; l < 3; ++l) {
    const int s0 = l * 2, s1 = l * 2 + 1;
    const ushort* wk = wt + (size_t)(l * 8 + 1) * 65536;
    const ushort* wv = wt + (size_t)(l * 8 + 2) * 65536;
    const ushort* wo0 = wt + (size_t)(l * 8 + 3) * 65536;
    const ushort* wq1 = wt + (size_t)(l * 8 + 4) * 65536;
    const ushort* wk1 = wt + (size_t)(l * 8 + 5) * 65536;
    const ushort* wv1 = wt + (size_t)(l * 8 + 6) * 65536;
    const ushort* wo1 = wt + (size_t)(l * 8 + 7) * 65536;
    // ---- mab0: fused K/V projection + attention (no K/V materialization) ----
    attn_fused<4><<<dim3(32, 8), 512, 0, stream>>>(
        q_all + l * 16384, xb, wk, ibk + s0 * 256, wv, ibv + s0 * 256, pmask, ob);
    ln4<<<512, 256, 0, stream>>>(ob, ob, ig0 + s0 * 256, ib0 + s0 * 256);
    gemm_bp<3, false, 256><<<16, 512, 0, stream>>>(
        ob, wo0, wo0, wo0, ibo + s0 * 256, ibo + s0 * 256, ibo + s0 * 256,
        hb, hb, hb, ig1 + s0 * 256, ib1 + s0 * 256, 1, 1);
    // ---- mab1 K,V (consume hb, tiny) ----
    gemm_bp<0, false, 128><<<64, 256, 0, stream>>>(
        hb, wk1, wv1, wv1, ibk + s1 * 256, ibv + s1 * 256, ibv + s1 * 256,
        kbw, vbw, vbw, nullptr, nullptr, 2, 4);
    // ---- mab1 fused: q-proj + attention + LN0 + Wo + LN1, xb in-place ----
    mab1_fused<<<dim3(32, 32), 512, 0, stream>>>(
        xb, wq1, ibq + s1 * 256, kbw, vbw, wo1, ibo + s1 * 256,
        ig0 + s1 * 256, ib0 + s1 * 256, ig1 + s1 * 256, ib1 + s1 * 256, xb);
  }
  // ---- PMA: fused K/V projection + attention ----
  attn_fused<2><<<dim3(32, 8), 512, 0, stream>>>(
      q_all + 49152, xb, wt + (size_t)25 * 65536, pbk, wt + (size_t)26 * 65536, pbv, pmask, ob);
  ln4<<<256, 256, 0, stream>>>(ob, ob, pg0, pb0);
  gemm_bp<3, true, 256><<<8, 512, 0, stream>>>(
      ob, wt + (size_t)27 * 65536, wt + (size_t)27 * 65536, wt + (size_t)27 * 65536,
      pbo, pbo, pbo, d_out, d_out, d_out, pg1, pb1, 1, 1);
}

// Round 17
// 791.884 us; speedup vs baseline: 1.0283x; 1.0150x over previous
//
#include <hip/hip_runtime.h>
#include <hip/hip_bf16.h>

// SetTransformer encoder forward. B=32,N=2048,D=256,H=8,dh=32,NI=64,NL=3,NS=32.
// Round 17: exact revert to r14 (measured best, 793us). r16's head-phase stagger
// regressed (FETCH 115->167MB): lockstep sharers get L2 miss-merging; stagger defeats
// it. All kernels now at empirically verified local optima (r10-r16 A/B matrix).

typedef __attribute__((ext_vector_type(8))) short short8;
typedef __attribute__((ext_vector_type(4))) float f32x4;
typedef __attribute__((ext_vector_type(4))) ushort ushort4v;

__device__ __forceinline__ ushort f2bf(float f) {
  uint u = __builtin_bit_cast(uint, f);
  u += 0x7fffu + ((u >> 16) & 1u);
  return (ushort)(u >> 16);
}
__device__ __forceinline__ float bf2f(ushort h) {
  uint u = (uint)h << 16;
  return __builtin_bit_cast(float, u);
}

// ---------------- weight prep: transpose 256x256 f32 [k][n] -> bf16 [n][k] ----------------
__global__ __launch_bounds__(256) void prep_weights(
    const float* __restrict__ Wq, const float* __restrict__ Wk,
    const float* __restrict__ Wv, const float* __restrict__ Wo,
    const float* __restrict__ pWq, const float* __restrict__ pWk,
    const float* __restrict__ pWv, const float* __restrict__ pWo,
    ushort* __restrict__ wt)
{
  __shared__ float tile[64][65];
  const int m = blockIdx.y;          // 0..27
  const int t = blockIdx.x;          // 0..15
  const int tr = (t >> 2) * 64;      // k block
  const int tc = (t & 3) * 64;       // n block
  const float* src;
  if (m < 24) {
    int l = m >> 3, s = (m >> 2) & 1, w = m & 3;
    const float* base = (w == 0) ? Wq : (w == 1) ? Wk : (w == 2) ? Wv : Wo;
    src = base + (size_t)(l * 2 + s) * 65536;
  } else {
    int w = m & 3;
    src = (w == 0) ? pWq : (w == 1) ? pWk : (w == 2) ? pWv : pWo;
  }
  const int tid = threadIdx.x;
  const int cn = tid & 63;
  const int rk = tid >> 6;
#pragma unroll
  for (int j = 0; j < 16; ++j) {
    int kl = rk + j * 4;
    tile[kl][cn] = src[(size_t)(tr + kl) * 256 + tc + cn];
  }
  __syncthreads();
  ushort* dst = wt + (size_t)m * 65536;
#pragma unroll
  for (int j = 0; j < 16; ++j) {
    int nl = rk + j * 4;
    dst[(size_t)(tc + nl) * 256 + tr + cn] = f2bf(tile[cn][nl]);
  }
}

// ---------------- input projection + exact gelu -> bf16, 8 rows/block ----------------
__global__ __launch_bounds__(256) void proj_gelu(
    const float* __restrict__ xv, const float* __restrict__ yt,
    const float* __restrict__ pW, const float* __restrict__ pb,
    ushort* __restrict__ xb)
{
  const int d = threadIdx.x;
  const int row0 = blockIdx.x * 8;
  const float w0 = pW[d], w1 = pW[256 + d], w2 = pW[512 + d], w3 = pW[768 + d];
  const float bz = pb[d];
#pragma unroll
  for (int rr = 0; rr < 8; ++rr) {
    int row = row0 + rr;
    float f0 = xv[(size_t)row * 3 + 0];
    float f1 = xv[(size_t)row * 3 + 1];
    float f2 = xv[(size_t)row * 3 + 2];
    float f3 = yt[row];
    float a = bz + f0 * w0 + f1 * w1 + f2 * w2 + f3 * w3;
    float g = 0.5f * a * (1.f + erff(a * 0.70710678118654752f));
    xb[(size_t)row * 256 + d] = f2bf(g);
  }
}

// ---------------- batched tiny q-projections (f32 A, M=64/32) ----------------
__global__ __launch_bounds__(256) void gemm_q(
    const float* __restrict__ iI, const float* __restrict__ pS,
    const ushort* __restrict__ wt, const float* __restrict__ ibq,
    const float* __restrict__ pbq, ushort* __restrict__ q_all)
{
  const int bq = blockIdx.x;
  const float* A; const ushort* Wt; const float* bias; ushort* out; int M;
  if (bq < 3) { A = iI + bq * 16384; Wt = wt + (size_t)(bq * 8) * 65536; bias = ibq + bq * 512; out = q_all + bq * 16384; M = 64; }
  else        { A = pS; Wt = wt + (size_t)24 * 65536; bias = pbq; out = q_all + 49152; M = 32; }
  const int tid = threadIdx.x;
  const int wave = tid >> 6, lane = tid & 63;
  const int l15 = lane & 15, l4 = lane >> 4, koff = l4 * 8;
  f32x4 acc[4][4];
#pragma unroll
  for (int i = 0; i < 4; ++i)
#pragma unroll
    for (int j = 0; j < 4; ++j) acc[i][j] = (f32x4)0.f;
#pragma unroll
  for (int ks = 0; ks < 8; ++ks) {
    short8 af[4];
#pragma unroll
    for (int mf = 0; mf < 4; ++mf) {
      if (mf * 16 < M) {
        const float* ap = A + (size_t)(mf * 16 + l15) * 256 + ks * 32 + koff;
        float4 f0 = *(const float4*)ap;
        float4 f1 = *(const float4*)(ap + 4);
        short8 sv;
        sv[0] = (short)f2bf(f0.x); sv[1] = (short)f2bf(f0.y);
        sv[2] = (short)f2bf(f0.z); sv[3] = (short)f2bf(f0.w);
        sv[4] = (short)f2bf(f1.x); sv[5] = (short)f2bf(f1.y);
        sv[6] = (short)f2bf(f1.z); sv[7] = (short)f2bf(f1.w);
        af[mf] = sv;
      } else af[mf] = (short8)0;
    }
#pragma unroll
    for (int nf = 0; nf < 4; ++nf) {
      short8 bf = *(const short8*)(Wt + (size_t)(wave * 64 + nf * 16 + l15) * 256 + ks * 32 + koff);
#pragma unroll
      for (int mf = 0; mf < 4; ++mf)
        acc[mf][nf] = __builtin_amdgcn_mfma_f32_16x16x32_bf16(af[mf], bf, acc[mf][nf], 0, 0, 0);
    }
  }
#pragma unroll
  for (int mf = 0; mf < 4; ++mf) {
    if (mf * 16 >= M) continue;
#pragma unroll
    for (int nf = 0; nf < 4; ++nf) {
      int col = wave * 64 + nf * 16 + l15;
      float bcol = bias[col];
#pragma unroll
      for (int r = 0; r < 4; ++r)
        out[(size_t)(mf * 16 + l4 * 4 + r) * 256 + col] = f2bf(acc[mf][nf][r] + bcol);
    }
  }
}

// ---------------- B-panel GEMM: out = epi(A @ W + bias) ----------------
// 1-D grid with XCD-colocating decode: bid = (x&7) + 8*(yz + nyz*(x>>3)).
template <int EPI, bool OUTF32, int COLS>
__global__ __launch_bounds__(COLS * 2, (COLS == 128) ? 4 : 2) void gemm_bp(
    const ushort* __restrict__ A,
    const ushort* __restrict__ Wt0, const ushort* __restrict__ Wt1, const ushort* __restrict__ Wt2,
    const float* __restrict__ b0, const float* __restrict__ b1, const float* __restrict__ b2,
    void* __restrict__ o0, void* __restrict__ o1, void* __restrict__ o2,
    const float* __restrict__ lng, const float* __restrict__ lnb,
    int ny, int nyz)
{
  constexpr int WC = COLS / 64;
  constexpr int PS = COLS * 64;
  constexpr int ROWB = COLS * 2;
  __shared__ __align__(16) char Bs[4 * PS];
  __shared__ float redbuf[(EPI == 3) ? 1280 : 4];
  const int bid = blockIdx.x;
  const int rest = bid >> 3;
  const int yz = rest % nyz;
  const int bx = ((rest / nyz) << 3) | (bid & 7);
  const int y = yz % ny;
  const int z = yz / ny;
  const ushort* Wt = (z == 0) ? Wt0 : ((z == 1) ? Wt1 : Wt2);
  const float* bias = (z == 0) ? b0 : ((z == 1) ? b1 : b2);
  void* outp = (z == 0) ? o0 : ((z == 1) ? o1 : o2);
  const int pcol = y * COLS;

  const int tid = threadIdx.x;
  const int wave = tid >> 6, lane = tid & 63;
  const int wc = wave % WC, wr = wave / WC;
  const int l15 = lane & 15, l4 = lane >> 4;
  const int row0 = bx * 128;
  const int sn = tid >> 1, sseg = tid & 1;

  f32x4 acc[4][4];
#pragma unroll
  for (int i = 0; i < 4; ++i)
#pragma unroll
    for (int j = 0; j < 4; ++j) acc[i][j] = (f32x4)0.f;

#pragma unroll
  for (int half = 0; half < 2; ++half) {
    if (half) __syncthreads();
    {
      const ushort* src = Wt + (size_t)(pcol + sn) * 256 + half * 128 + sseg * 64;
#pragma unroll
      for (int c = 0; c < 8; ++c) {
        uint4 w = *(const uint4*)(src + c * 8);
        int plane = sseg * 2 + (c >> 2);
        char* dst = Bs + plane * PS + sn * 64 + (((c & 3) * 16) ^ (((sn >> 1) & 3) << 4));
        *(uint4*)dst = w;
      }
    }
    __syncthreads();
#pragma unroll
    for (int ks = 0; ks < 4; ++ks) {
      short8 af[4];
#pragma unroll
      for (int mfa = 0; mfa < 4; ++mfa)
        af[mfa] = *(const short8*)(A + (size_t)(row0 + wr * 64 + mfa * 16 + l15) * 256 + half * 128 + ks * 32 + l4 * 8);
#pragma unroll
      for (int nfb = 0; nfb < 4; ++nfb) {
        int n = wc * 64 + nfb * 16 + l15;
        short8 bf = *(const short8*)(Bs + ks * PS + n * 64 + ((l4 * 16) ^ (((n >> 1) & 3) << 4)));
#pragma unroll
        for (int mfa = 0; mfa < 4; ++mfa)
          acc[mfa][nfb] = __builtin_amdgcn_mfma_f32_16x16x32_bf16(bf, af[mfa], acc[mfa][nfb], 0, 0, 0);
      }
    }
  }

  if constexpr (EPI == 0) {
    __syncthreads();
#pragma unroll
    for (int nfb = 0; nfb < 4; ++nfb) {
      f32x4 bv = *(const f32x4*)(bias + pcol + wc * 64 + nfb * 16 + l4 * 4);
      int colb = wc * 128 + nfb * 32 + l4 * 8;
#pragma unroll
      for (int mfa = 0; mfa < 4; ++mfa) {
        int row = wr * 64 + mfa * 16 + l15;
        ushort4v pk;
#pragma unroll
        for (int i = 0; i < 4; ++i) pk[i] = f2bf(acc[mfa][nfb][i] + bv[i]);
        *(ushort4v*)(Bs + row * ROWB + (colb ^ ((row & 7) << 4))) = pk;
      }
    }
    __syncthreads();
    const int srow = tid >> 2, seg = tid & 3;
#pragma unroll
    for (int rr = 0; rr < 2; ++rr) {
      int row = srow + rr * 64;
      int x = (row & 7) << 4;
      ushort* gdst = (ushort*)outp + (size_t)(row0 + row) * 256 + pcol;
#pragma unroll
      for (int it = 0; it < 4; ++it) {
        int colb = seg * 16 + it * 64;
        uint4 v = *(const uint4*)(Bs + row * ROWB + (colb ^ x));
        *(uint4*)(gdst + colb / 2) = v;
      }
    }
  } else {
    float* red1 = redbuf;
    float* red2 = redbuf + 512;
    float* mv_ = redbuf + 1024;
    float* rv_ = redbuf + 1152;
    float s1[4] = {0.f, 0.f, 0.f, 0.f}, s2[4] = {0.f, 0.f, 0.f, 0.f};
#pragma unroll
    for (int nfb = 0; nfb < 4; ++nfb) {
      int col0 = wc * 64 + nfb * 16 + l4 * 4;
      f32x4 bv = *(const f32x4*)(bias + col0);
#pragma unroll
      for (int mfa = 0; mfa < 4; ++mfa) {
        size_t row = (size_t)row0 + wr * 64 + mfa * 16 + l15;
        ushort4v rz = *(const ushort4v*)(A + row * 256 + col0);
#pragma unroll
        for (int i = 0; i < 4; ++i) {
          float zz = bf2f(rz[i]) + fmaxf(acc[mfa][nfb][i] + bv[i], 0.f);
          acc[mfa][nfb][i] = zz;
          s1[mfa] += zz;
          s2[mfa] += zz * zz;
        }
      }
    }
#pragma unroll
    for (int mfa = 0; mfa < 4; ++mfa) {
      s1[mfa] += __shfl_xor(s1[mfa], 16); s1[mfa] += __shfl_xor(s1[mfa], 32);
      s2[mfa] += __shfl_xor(s2[mfa], 16); s2[mfa] += __shfl_xor(s2[mfa], 32);
    }
    if (l4 == 0) {
#pragma unroll
      for (int mfa = 0; mfa < 4; ++mfa) {
        red1[wc * 128 + wr * 64 + mfa * 16 + l15] = s1[mfa];
        red2[wc * 128 + wr * 64 + mfa * 16 + l15] = s2[mfa];
      }
    }
    __syncthreads();
    if (tid < 128) {
      float m1 = red1[tid] + red1[128 + tid] + red1[256 + tid] + red1[384 + tid];
      float m2 = red2[tid] + red2[128 + tid] + red2[256 + tid] + red2[384 + tid];
      float mean = m1 * 0.00390625f;
      float var = m2 * 0.00390625f - mean * mean;
      mv_[tid] = mean;
      rv_[tid] = rsqrtf(var + 1e-5f);
    }
    __syncthreads();
#pragma unroll
    for (int nfb = 0; nfb < 4; ++nfb) {
      int col0 = wc * 64 + nfb * 16 + l4 * 4;
      f32x4 gg = *(const f32x4*)(lng + col0);
      f32x4 bb = *(const f32x4*)(lnb + col0);
      int colb = col0 * 2;
#pragma unroll
      for (int mfa = 0; mfa < 4; ++mfa) {
        int lr = wr * 64 + mfa * 16 + l15;
        float mean = mv_[lr], rs = rv_[lr];
        if constexpr (OUTF32) {
          f32x4 w;
#pragma unroll
          for (int i = 0; i < 4; ++i) w[i] = (acc[mfa][nfb][i] - mean) * rs * gg[i] + bb[i];
          *(f32x4*)((float*)outp + ((size_t)row0 + lr) * 256 + col0) = w;
        } else {
          ushort4v pk;
#pragma unroll
          for (int i = 0; i < 4; ++i) pk[i] = f2bf((acc[mfa][nfb][i] - mean) * rs * gg[i] + bb[i]);
          *(ushort4v*)(Bs + lr * ROWB + (colb ^ ((lr & 7) << 4))) = pk;
        }
      }
    }
    if constexpr (!OUTF32) {
      __syncthreads();
      const int srow = tid >> 2, seg = tid & 3;
      int x = (srow & 7) << 4;
      ushort* gdst = (ushort*)outp + (size_t)(row0 + srow) * 256;
#pragma unroll
      for (int it = 0; it < 8; ++it) {
        int colb = seg * 16 + it * 64;
        uint4 v = *(const uint4*)(Bs + srow * ROWB + (colb ^ x));
        *(uint4*)(gdst + colb / 2) = v;
      }
    }
  }
}

// ---------------- attn_fused: on-the-fly K/V projection + flash attention ----------------
// nq small (64/32), nk=2048, masked, q shared across batch. grid(b=32, h=8) so the 8
// head-blocks of a batch share one XCD L2 (bid % 8 == b % 8) -> lockstep chunk access
// lets L2 merge concurrent misses (r16 stagger A/B proved lockstep is faster).
template <int MF>
__global__ __launch_bounds__(512) void attn_fused(
    const ushort* __restrict__ qb, const ushort* __restrict__ xbuf,
    const ushort* __restrict__ wk, const float* __restrict__ bk,
    const ushort* __restrict__ wv, const float* __restrict__ bv,
    const float* __restrict__ mask, ushort* __restrict__ O)
{
  __shared__ __align__(16) ushort Ps[8][64][72];   // 72KB; merge overlay at end
  __shared__ __align__(16) ushort Vt[8][32][72];   // 36KB
  __shared__ __align__(16) ushort Kc[8][64][40];   // 40KB: projected K chunk
  const int b = blockIdx.x, h = blockIdx.y;
  const int tid = threadIdx.x;
  const int w = tid >> 6, lane = tid & 63;
  const int l15 = lane & 15, l4 = lane >> 4;
  const int koff = l4 * 8;
  const int kvbase = b * 2048;

  short8 qf[MF];
#pragma unroll
  for (int mf = 0; mf < MF; ++mf)
    qf[mf] = *(const short8*)(qb + (size_t)(mf * 16 + l15) * 256 + h * 32 + koff);

  f32x4 bkv[2], bvv[2];
#pragma unroll
  for (int nfb = 0; nfb < 2; ++nfb) {
    bkv[nfb] = *(const f32x4*)(bk + h * 32 + nfb * 16 + l4 * 4);
    bvv[nfb] = *(const f32x4*)(bv + h * 32 + nfb * 16 + l4 * 4);
  }

  f32x4 Oa[MF][2];
  float Mr[MF][4], Lr[MF][4];
#pragma unroll
  for (int mf = 0; mf < MF; ++mf) {
    Oa[mf][0] = (f32x4)0.f; Oa[mf][1] = (f32x4)0.f;
#pragma unroll
    for (int r = 0; r < 4; ++r) { Mr[mf][r] = -1e30f; Lr[mf][r] = 0.f; }
  }

  for (int c = 0; c < 4; ++c) {
    const int kc = w * 256 + c * 64;
    // ---- project K,V for this 64-key chunk (swapped MFMA: lane=(key l15, col l4*4+i)) ----
    f32x4 ak[4][2], av[4][2];
#pragma unroll
    for (int i = 0; i < 4; ++i) {
      ak[i][0] = (f32x4)0.f; ak[i][1] = (f32x4)0.f;
      av[i][0] = (f32x4)0.f; av[i][1] = (f32x4)0.f;
    }
#pragma unroll
    for (int ks = 0; ks < 8; ++ks) {
      short8 af[4];
#pragma unroll
      for (int mfa = 0; mfa < 4; ++mfa)
        af[mfa] = *(const short8*)(xbuf + (size_t)(kvbase + kc + mfa * 16 + l15) * 256 + ks * 32 + koff);
#pragma unroll
      for (int nfb = 0; nfb < 2; ++nfb) {
        int n = h * 32 + nfb * 16 + l15;
        short8 wkf = *(const short8*)(wk + (size_t)n * 256 + ks * 32 + koff);
        short8 wvf = *(const short8*)(wv + (size_t)n * 256 + ks * 32 + koff);
#pragma unroll
        for (int mfa = 0; mfa < 4; ++mfa) {
          ak[mfa][nfb] = __builtin_amdgcn_mfma_f32_16x16x32_bf16(wkf, af[mfa], ak[mfa][nfb], 0, 0, 0);
          av[mfa][nfb] = __builtin_amdgcn_mfma_f32_16x16x32_bf16(wvf, af[mfa], av[mfa][nfb], 0, 0, 0);
        }
      }
    }
    // stage K chunk: Kc[key][col] bf16 (+bias) — wave-private, in-order
#pragma unroll
    for (int nfb = 0; nfb < 2; ++nfb)
#pragma unroll
      for (int mfa = 0; mfa < 4; ++mfa) {
        ushort4v pk;
#pragma unroll
        for (int i = 0; i < 4; ++i) pk[i] = f2bf(ak[mfa][nfb][i] + bkv[nfb][i]);
        *(ushort4v*)&Kc[w][mfa * 16 + l15][nfb * 16 + l4 * 4] = pk;
      }
    // stage V^T: Vt[col][key] bf16 (+bias)
#pragma unroll
    for (int nfb = 0; nfb < 2; ++nfb)
#pragma unroll
      for (int mfa = 0; mfa < 4; ++mfa)
#pragma unroll
        for (int i = 0; i < 4; ++i)
          Vt[w][nfb * 16 + l4 * 4 + i][mfa * 16 + l15] = f2bf(av[mfa][nfb][i] + bvv[nfb][i]);

    // ---- S = (Q K^T)/16 + mask ----
    f32x4 S[MF][4];
#pragma unroll
    for (int nf = 0; nf < 4; ++nf) {
      short8 kf = *(const short8*)&Kc[w][nf * 16 + l15][koff];
#pragma unroll
      for (int mf = 0; mf < MF; ++mf)
        S[mf][nf] = __builtin_amdgcn_mfma_f32_16x16x32_bf16(qf[mf], kf, (f32x4)0.f, 0, 0, 0);
    }
    float mv[4];
#pragma unroll
    for (int nf = 0; nf < 4; ++nf)
      mv[nf] = mask[(size_t)b * 2048 + kc + nf * 16 + l15];
#pragma unroll
    for (int mf = 0; mf < MF; ++mf)
#pragma unroll
      for (int nf = 0; nf < 4; ++nf)
#pragma unroll
        for (int r = 0; r < 4; ++r) {
          float s = S[mf][nf][r] * 0.0625f;
          S[mf][nf][r] = (mv[nf] != 0.f) ? s : -1e4f;
        }
#pragma unroll
    for (int mf = 0; mf < MF; ++mf)
#pragma unroll
      for (int r = 0; r < 4; ++r) {
        float pm = fmaxf(fmaxf(S[mf][0][r], S[mf][1][r]), fmaxf(S[mf][2][r], S[mf][3][r]));
        pm = fmaxf(pm, __shfl_xor(pm, 1));
        pm = fmaxf(pm, __shfl_xor(pm, 2));
        pm = fmaxf(pm, __shfl_xor(pm, 4));
        pm = fmaxf(pm, __shfl_xor(pm, 8));
        float Mnew = fmaxf(Mr[mf][r], pm);
        float corr = __expf(Mr[mf][r] - Mnew);
        Mr[mf][r] = Mnew;
        float rs = 0.f;
#pragma unroll
        for (int nf = 0; nf < 4; ++nf) {
          float p = __expf(S[mf][nf][r] - Mnew);
          S[mf][nf][r] = p;
          rs += p;
        }
        rs += __shfl_xor(rs, 1);
        rs += __shfl_xor(rs, 2);
        rs += __shfl_xor(rs, 4);
        rs += __shfl_xor(rs, 8);
        Lr[mf][r] = Lr[mf][r] * corr + rs;
        Oa[mf][0][r] *= corr;
        Oa[mf][1][r] *= corr;
      }
#pragma unroll
    for (int mf = 0; mf < MF; ++mf)
#pragma unroll
      for (int nf = 0; nf < 4; ++nf)
#pragma unroll
        for (int r = 0; r < 4; ++r)
          Ps[w][mf * 16 + l4 * 4 + r][nf * 16 + l15] = f2bf(S[mf][nf][r]);
#pragma unroll
    for (int ks = 0; ks < 2; ++ks) {
      short8 pf[MF];
#pragma unroll
      for (int mf = 0; mf < MF; ++mf)
        pf[mf] = *(const short8*)&Ps[w][mf * 16 + l15][ks * 32 + koff];
#pragma unroll
      for (int nf2 = 0; nf2 < 2; ++nf2) {
        short8 vf = *(const short8*)&Vt[w][nf2 * 16 + l15][ks * 32 + koff];
#pragma unroll
        for (int mf = 0; mf < MF; ++mf)
          Oa[mf][nf2] = __builtin_amdgcn_mfma_f32_16x16x32_bf16(pf[mf], vf, Oa[mf][nf2], 0, 0, 0);
      }
    }
  }

  // ---- merge 8 partials via LDS (overlay on Ps) ----
  __syncthreads();
  float* Mw = (float*)&Ps[0][0][0];
  float* Lw = Mw + 512;
  float* Ow = Lw + 512;  // [8][64][33]
#pragma unroll
  for (int mf = 0; mf < MF; ++mf)
#pragma unroll
    for (int r = 0; r < 4; ++r) {
      int row = mf * 16 + l4 * 4 + r;
      if (l15 == 0) { Mw[w * 64 + row] = Mr[mf][r]; Lw[w * 64 + row] = Lr[mf][r]; }
#pragma unroll
      for (int nf2 = 0; nf2 < 2; ++nf2)
        Ow[(w * 64 + row) * 33 + nf2 * 16 + l15] = Oa[mf][nf2][r];
    }
  __syncthreads();
  const int NQ = MF * 16;
  int row = tid >> 3, dg = tid & 7;
  if (row < NQ) {
    float mm = -1e30f;
#pragma unroll
    for (int s = 0; s < 8; ++s) mm = fmaxf(mm, Mw[s * 64 + row]);
    float den = 0.f, es[8];
#pragma unroll
    for (int s = 0; s < 8; ++s) {
      es[s] = __expf(Mw[s * 64 + row] - mm);
      den += Lw[s * 64 + row] * es[s];
    }
    float invden = 1.f / den;
    ushort4v pk;
#pragma unroll
    for (int i = 0; i < 4; ++i) {
      int d = dg * 4 + i;
      float num = 0.f;
#pragma unroll
      for (int s = 0; s < 8; ++s) num += Ow[(s * 64 + row) * 33 + d] * es[s];
      float qv = bf2f(qb[(size_t)row * 256 + h * 32 + d]);
      pk[i] = f2bf(qv + num * invden);
    }
    *(ushort4v*)(O + (size_t)(b * NQ + row) * 256 + h * 32 + dg * 4) = pk;
  }
}

// ---------------- mab1_fused (r10 config): q-proj + attention(nk=64) + LN0 + Wo + LN1 ----
// grid(qt=32, b=32), block 512 = 8 waves = 8 heads over the same 64 q-rows.
__global__ __launch_bounds__(512, 4) void mab1_fused(
    const ushort* __restrict__ xb, const ushort* __restrict__ wq,
    const float* __restrict__ bq,
    const ushort* __restrict__ kb, const ushort* __restrict__ vb,
    const ushort* __restrict__ wo, const float* __restrict__ bo,
    const float* __restrict__ g0, const float* __restrict__ b0v,
    const float* __restrict__ g1, const float* __restrict__ b1v,
    ushort* __restrict__ outb)
{
  __shared__ __align__(16) ushort Qs[8][64][40];   // 40KB q tiles; later o_s[64][264]
  __shared__ __align__(16) ushort Psh[8][16][40];  // 10KB P half-tile (per-mf staging)
  __shared__ __align__(16) ushort Vth[8][32][40];  // 20KB V^T half (32 keys)
  __shared__ float red1[8][64], red2[8][64], mv_[64], rv_[64];
  ushort* o_s = &Qs[0][0][0];
  constexpr int OS = 264;

  const int qt = blockIdx.x, b = blockIdx.y;
  const int tid = threadIdx.x;
  const int w = tid >> 6, lane = tid & 63;
  const int l15 = lane & 15, l4 = lane >> 4;
  const int koff = l4 * 8;
  const size_t row0 = (size_t)b * 2048 + qt * 64;
  const int kvbase = b * 64;
  const int h = w;

  short8 kf[4];
#pragma unroll
  for (int nf = 0; nf < 4; ++nf)
    kf[nf] = *(const short8*)(kb + (size_t)(kvbase + nf * 16 + l15) * 256 + h * 32 + koff);
  const int key = lane & 31, dh2 = lane >> 5;
  short8 vvB0, vvB1;
  {
    const ushort* vsrcA = vb + (size_t)(kvbase + key) * 256 + h * 32 + dh2 * 16;
    const ushort* vsrcB = vb + (size_t)(kvbase + 32 + key) * 256 + h * 32 + dh2 * 16;
    short8 vvA0 = *(const short8*)vsrcA;
    short8 vvA1 = *(const short8*)(vsrcA + 8);
    vvB0 = *(const short8*)vsrcB;
    vvB1 = *(const short8*)(vsrcB + 8);
#pragma unroll
    for (int j = 0; j < 8; ++j) Vth[w][dh2 * 16 + j][key] = (ushort)vvA0[j];
#pragma unroll
    for (int j = 0; j < 8; ++j) Vth[w][dh2 * 16 + 8 + j][key] = (ushort)vvA1[j];
  }

  {
    f32x4 qa[4][2];
#pragma unroll
    for (int i = 0; i < 4; ++i) { qa[i][0] = (f32x4)0.f; qa[i][1] = (f32x4)0.f; }
#pragma unroll
    for (int ks = 0; ks < 8; ++ks) {
      short8 af[4];
#pragma unroll
      for (int mfa = 0; mfa < 4; ++mfa)
        af[mfa] = *(const short8*)(xb + (row0 + mfa * 16 + l15) * 256 + ks * 32 + koff);
#pragma unroll
      for (int nfb = 0; nfb < 2; ++nfb) {
        int n = w * 32 + nfb * 16 + l15;
        short8 bf = *(const short8*)(wq + (size_t)n * 256 + ks * 32 + koff);
#pragma unroll
        for (int mfa = 0; mfa < 4; ++mfa)
          qa[mfa][nfb] = __builtin_amdgcn_mfma_f32_16x16x32_bf16(bf, af[mfa], qa[mfa][nfb], 0, 0, 0);
      }
    }
#pragma unroll
    for (int nfb = 0; nfb < 2; ++nfb) {
      f32x4 bvq = *(const f32x4*)(bq + w * 32 + nfb * 16 + l4 * 4);
#pragma unroll
      for (int mfa = 0; mfa < 4; ++mfa) {
        ushort4v pk;
#pragma unroll
        for (int i = 0; i < 4; ++i) pk[i] = f2bf(qa[mfa][nfb][i] + bvq[i]);
        *(ushort4v*)&Qs[w][mfa * 16 + l15][nfb * 16 + l4 * 4] = pk;
      }
    }
  }

  short8 qf[4];
#pragma unroll
  for (int mf = 0; mf < 4; ++mf)
    qf[mf] = *(const short8*)&Qs[w][mf * 16 + l15][koff];

  f32x4 S[4][4];
#pragma unroll
  for (int nf = 0; nf < 4; ++nf) {
#pragma unroll
    for (int mf = 0; mf < 4; ++mf)
      S[mf][nf] = __builtin_amdgcn_mfma_f32_16x16x32_bf16(qf[mf], kf[nf], (f32x4)0.f, 0, 0, 0);
  }
  float Lr[4][4];
#pragma unroll
  for (int mf = 0; mf < 4; ++mf)
#pragma unroll
    for (int r = 0; r < 4; ++r) {
      float pm = fmaxf(fmaxf(S[mf][0][r], S[mf][1][r]), fmaxf(S[mf][2][r], S[mf][3][r])) * 0.0625f;
      pm = fmaxf(pm, __shfl_xor(pm, 1));
      pm = fmaxf(pm, __shfl_xor(pm, 2));
      pm = fmaxf(pm, __shfl_xor(pm, 4));
      pm = fmaxf(pm, __shfl_xor(pm, 8));
      float rs = 0.f;
#pragma unroll
      for (int nf = 0; nf < 4; ++nf) {
        float pp = __expf(S[mf][nf][r] * 0.0625f - pm);
        S[mf][nf][r] = pp;
        rs += pp;
      }
      rs += __shfl_xor(rs, 1);
      rs += __shfl_xor(rs, 2);
      rs += __shfl_xor(rs, 4);
      rs += __shfl_xor(rs, 8);
      Lr[mf][r] = rs;
    }

  f32x4 Oa[4][2];
#pragma unroll
  for (int mf = 0; mf < 4; ++mf) { Oa[mf][0] = (f32x4)0.f; Oa[mf][1] = (f32x4)0.f; }
#pragma unroll
  for (int mf = 0; mf < 4; ++mf) {
#pragma unroll
    for (int nf = 0; nf < 2; ++nf)
#pragma unroll
      for (int r = 0; r < 4; ++r)
        Psh[w][l4 * 4 + r][nf * 16 + l15] = f2bf(S[mf][nf][r]);
    short8 pf = *(const short8*)&Psh[w][l15][koff];
#pragma unroll
    for (int nf2 = 0; nf2 < 2; ++nf2) {
      short8 vf = *(const short8*)&Vth[w][nf2 * 16 + l15][koff];
      Oa[mf][nf2] = __builtin_amdgcn_mfma_f32_16x16x32_bf16(pf, vf, Oa[mf][nf2], 0, 0, 0);
    }
  }
#pragma unroll
  for (int j = 0; j < 8; ++j) Vth[w][dh2 * 16 + j][key] = (ushort)vvB0[j];
#pragma unroll
  for (int j = 0; j < 8; ++j) Vth[w][dh2 * 16 + 8 + j][key] = (ushort)vvB1[j];
#pragma unroll
  for (int mf = 0; mf < 4; ++mf) {
#pragma unroll
    for (int nf = 0; nf < 2; ++nf)
#pragma unroll
      for (int r = 0; r < 4; ++r)
        Psh[w][l4 * 4 + r][nf * 16 + l15] = f2bf(S[mf][nf + 2][r]);
    short8 pf = *(const short8*)&Psh[w][l15][koff];
#pragma unroll
    for (int nf2 = 0; nf2 < 2; ++nf2) {
      short8 vf = *(const short8*)&Vth[w][nf2 * 16 + l15][koff];
      Oa[mf][nf2] = __builtin_amdgcn_mfma_f32_16x16x32_bf16(pf, vf, Oa[mf][nf2], 0, 0, 0);
    }
  }

  {
    float s1[4][4], s2[4][4];
#pragma unroll
    for (int mf = 0; mf < 4; ++mf)
#pragma unroll
      for (int r = 0; r < 4; ++r) {
        float invL = 1.f / Lr[mf][r];
        s1[mf][r] = 0.f; s2[mf][r] = 0.f;
#pragma unroll
        for (int nf2 = 0; nf2 < 2; ++nf2) {
          float qv = bf2f(Qs[w][mf * 16 + l4 * 4 + r][nf2 * 16 + l15]);
          float z = qv + Oa[mf][nf2][r] * invL;
          Oa[mf][nf2][r] = z;
          s1[mf][r] += z;
          s2[mf][r] += z * z;
        }
#pragma unroll
        for (int off = 1; off < 16; off <<= 1) {
          s1[mf][r] += __shfl_xor(s1[mf][r], off);
          s2[mf][r] += __shfl_xor(s2[mf][r], off);
        }
        if (l15 == 0) {
          int row = mf * 16 + l4 * 4 + r;
          red1[w][row] = s1[mf][r];
          red2[w][row] = s2[mf][r];
        }
      }
  }
  __syncthreads();
  if (tid < 64) {
    float m1 = 0.f, m2 = 0.f;
#pragma unroll
    for (int s = 0; s < 8; ++s) { m1 += red1[s][tid]; m2 += red2[s][tid]; }
    float mean = m1 * 0.00390625f;
    float var = m2 * 0.00390625f - mean * mean;
    mv_[tid] = mean;
    rv_[tid] = rsqrtf(var + 1e-5f);
  }
  __syncthreads();
#pragma unroll
  for (int nf2 = 0; nf2 < 2; ++nf2) {
    int col = h * 32 + nf2 * 16 + l15;
    float gc = g0[col], bc = b0v[col];
#pragma unroll
    for (int mf = 0; mf < 4; ++mf)
#pragma unroll
      for (int r = 0; r < 4; ++r) {
        int row = mf * 16 + l4 * 4 + r;
        float v = (Oa[mf][nf2][r] - mv_[row]) * rv_[row] * gc + bc;
        o_s[row * OS + col] = f2bf(v);
      }
  }
  __syncthreads();

  f32x4 oa[4][2];
#pragma unroll
  for (int i = 0; i < 4; ++i) { oa[i][0] = (f32x4)0.f; oa[i][1] = (f32x4)0.f; }
#pragma unroll
  for (int ks = 0; ks < 8; ++ks) {
    short8 af[4];
#pragma unroll
    for (int mfa = 0; mfa < 4; ++mfa)
      af[mfa] = *(const short8*)&o_s[(mfa * 16 + l15) * OS + ks * 32 + koff];
#pragma unroll
    for (int nfb = 0; nfb < 2; ++nfb) {
      int n = w * 32 + nfb * 16 + l15;
      short8 bf = *(const short8*)(wo + (size_t)n * 256 + ks * 32 + koff);
#pragma unroll
      for (int mfa = 0; mfa < 4; ++mfa)
        oa[mfa][nfb] = __builtin_amdgcn_mfma_f32_16x16x32_bf16(bf, af[mfa], oa[mfa][nfb], 0, 0, 0);
    }
  }
  float t1[4] = {0.f, 0.f, 0.f, 0.f}, t2[4] = {0.f, 0.f, 0.f, 0.f};
#pragma unroll
  for (int nfb = 0; nfb < 2; ++nfb) {
    int col0 = w * 32 + nfb * 16 + l4 * 4;
    f32x4 bvo = *(const f32x4*)(bo + col0);
#pragma unroll
    for (int mfa = 0; mfa < 4; ++mfa) {
      int row = mfa * 16 + l15;
      ushort4v rz = *(const ushort4v*)&o_s[row * OS + col0];
#pragma unroll
      for (int i = 0; i < 4; ++i) {
        float zz = bf2f(rz[i]) + fmaxf(oa[mfa][nfb][i] + bvo[i], 0.f);
        oa[mfa][nfb][i] = zz;
        t1[mfa] += zz;
        t2[mfa] += zz * zz;
      }
    }
  }
#pragma unroll
  for (int mfa = 0; mfa < 4; ++mfa) {
    t1[mfa] += __shfl_xor(t1[mfa], 16); t1[mfa] += __shfl_xor(t1[mfa], 32);
    t2[mfa] += __shfl_xor(t2[mfa], 16); t2[mfa] += __shfl_xor(t2[mfa], 32);
  }
  if (l4 == 0) {
#pragma unroll
    for (int mfa = 0; mfa < 4; ++mfa) {
      red1[w][mfa * 16 + l15] = t1[mfa];
      red2[w][mfa * 16 + l15] = t2[mfa];
    }
  }
  __syncthreads();
  if (tid < 64) {
    float m1 = 0.f, m2 = 0.f;
#pragma unroll
    for (int s = 0; s < 8; ++s) { m1 += red1[s][tid]; m2 += red2[s][tid]; }
    float mean = m1 * 0.00390625f;
    float var = m2 * 0.00390625f - mean * mean;
    mv_[tid] = mean;
    rv_[tid] = rsqrtf(var + 1e-5f);
  }
  __syncthreads();
#pragma unroll
  for (int nfb = 0; nfb < 2; ++nfb) {
    int col0 = w * 32 + nfb * 16 + l4 * 4;
    f32x4 gg = *(const f32x4*)(g1 + col0);
    f32x4 bb = *(const f32x4*)(b1v + col0);
#pragma unroll
    for (int mfa = 0; mfa < 4; ++mfa) {
      int row = mfa * 16 + l15;
      ushort4v pk;
#pragma unroll
      for (int i = 0; i < 4; ++i)
        pk[i] = f2bf((oa[mfa][nfb][i] - mv_[row]) * rv_[row] * gg[i] + bb[i]);
      *(ushort4v*)&o_s[row * OS + col0] = pk;
    }
  }
  __syncthreads();
  {
    const int r_ = tid >> 3, sg = tid & 7;
    ushort* gdst = outb + (row0 + r_) * 256 + sg * 32;
    const ushort* src = &o_s[r_ * OS + sg * 32];
#pragma unroll
    for (int it = 0; it < 4; ++it) {
      uint4 v = *(const uint4*)(src + it * 8);
      *(uint4*)(gdst + it * 8) = v;
    }
  }
}

// ---------------- small LayerNorm: bf16 in/out, wave per row ----------------
__global__ __launch_bounds__(256) void ln4(
    const ushort* __restrict__ in, ushort* __restrict__ out,
    const float* __restrict__ g, const float* __restrict__ bb)
{
  const int w = threadIdx.x >> 6, lane = threadIdx.x & 63;
  const size_t row = (size_t)blockIdx.x * 4 + w;
  ushort4v u = *(const ushort4v*)(in + row * 256 + lane * 4);
  float v[4];
#pragma unroll
  for (int i = 0; i < 4; ++i) v[i] = bf2f(u[i]);
  float s1 = v[0] + v[1] + v[2] + v[3];
  float s2 = v[0] * v[0] + v[1] * v[1] + v[2] * v[2] + v[3] * v[3];
#pragma unroll
  for (int off = 1; off < 64; off <<= 1) {
    s1 += __shfl_xor(s1, off);
    s2 += __shfl_xor(s2, off);
  }
  float mean = s1 * 0.00390625f;
  float var = s2 * 0.00390625f - mean * mean;
  float rs = rsqrtf(var + 1e-5f);
  f32x4 gg = *(const f32x4*)(g + lane * 4);
  f32x4 bv = *(const f32x4*)(bb + lane * 4);
  ushort4v p;
#pragma unroll
  for (int i = 0; i < 4; ++i) p[i] = f2bf((v[i] - mean) * rs * gg[i] + bv[i]);
  *(ushort4v*)(out + row * 256 + lane * 4) = p;
}

extern "C" void kernel_launch(void* const* d_in, const int* in_sizes, int n_in,
                              void* d_out, int out_size, void* d_ws, size_t ws_size,
                              hipStream_t stream) {
  const float* xv = (const float*)d_in[0];
  const float* yt = (const float*)d_in[1];
  const float* pmask = (const float*)d_in[2];
  const float* prW = (const float*)d_in[3];
  const float* prb = (const float*)d_in[4];
  const float* iI = (const float*)d_in[5];
  const float* iWq = (const float*)d_in[6];
  const float* ibq = (const float*)d_in[7];
  const float* iWk = (const float*)d_in[8];
  const float* ibk = (const float*)d_in[9];
  const float* iWv = (const float*)d_in[10];
  const float* ibv = (const float*)d_in[11];
  const float* iWo = (const float*)d_in[12];
  const float* ibo = (const float*)d_in[13];
  const float* ig0 = (const float*)d_in[14];
  const float* ib0 = (const float*)d_in[15];
  const float* ig1 = (const float*)d_in[16];
  const float* ib1 = (const float*)d_in[17];
  const float* pS = (const float*)d_in[18];
  const float* pWq = (const float*)d_in[19];
  const float* pbq = (const float*)d_in[20];
  const float* pWk = (const float*)d_in[21];
  const float* pbk = (const float*)d_in[22];
  const float* pWv = (const float*)d_in[23];
  const float* pbv = (const float*)d_in[24];
  const float* pWo = (const float*)d_in[25];
  const float* pbo = (const float*)d_in[26];
  const float* pg0 = (const float*)d_in[27];
  const float* pb0 = (const float*)d_in[28];
  const float* pg1 = (const float*)d_in[29];
  const float* pb1 = (const float*)d_in[30];

  char* ws = (char*)d_ws;
  if (ws_size < 172621824u) return;
  ushort* xb = (ushort*)(ws + 0);              // 32MB (B*N x 256)
  ushort* ob = (ushort*)(ws + 33554432);       // 32MB (attn/LN scratch)
  ushort* hb = (ushort*)(ws + 67108864);       // 1MB  (B*NI x 256)
  ushort* kbw = (ushort*)(ws + 101711872);     // 32MB (mab1 K)
  ushort* vbw = (ushort*)(ws + 135266304);     // 32MB (mab1 V)
  ushort* wt = (ushort*)(ws + 168820736);      // 3.5MB transposed weights
  ushort* q_all = (ushort*)(ws + 172490752);   // 112KB tiny-q outputs

  prep_weights<<<dim3(16, 28), 256, 0, stream>>>(iWq, iWk, iWv, iWo, pWq, pWk, pWv, pWo, wt);
  proj_gelu<<<8192, 256, 0, stream>>>(xv, yt, prW, prb, xb);
  gemm_q<<<4, 256, 0, stream>>>(iI, pS, wt, ibq, pbq, q_all);

  for (int l = 0; l < 3; ++l) {
    const int s0 = l * 2, s1 = l * 2 + 1;
    const ushort* wk = wt + (size_t)(l * 8 + 1) * 65536;
    const ushort* wv = wt + (size_t)(l * 8 + 2) * 65536;
    const ushort* wo0 = wt + (size_t)(l * 8 + 3) * 65536;
    const ushort* wq1 = wt + (size_t)(l * 8 + 4) * 65536;
    const ushort* wk1 = wt + (size_t)(l * 8 + 5) * 65536;
    const ushort* wv1 = wt + (size_t)(l * 8 + 6) * 65536;
    const ushort* wo1 = wt + (size_t)(l * 8 + 7) * 65536;
    // ---- mab0: fused K/V projection + attention (no K/V materialization) ----
    attn_fused<4><<<dim3(32, 8), 512, 0, stream>>>(
        q_all + l * 16384, xb, wk, ibk + s0 * 256, wv, ibv + s0 * 256, pmask, ob);
    ln4<<<512, 256, 0, stream>>>(ob, ob, ig0 + s0 * 256, ib0 + s0 * 256);
    gemm_bp<3, false, 256><<<16, 512, 0, stream>>>(
        ob, wo0, wo0, wo0, ibo + s0 * 256, ibo + s0 * 256, ibo + s0 * 256,
        hb, hb, hb, ig1 + s0 * 256, ib1 + s0 * 256, 1, 1);
    // ---- mab1 K,V (consume hb, tiny) ----
    gemm_bp<0, false, 128><<<64, 256, 0, stream>>>(
        hb, wk1, wv1, wv1, ibk + s1 * 256, ibv + s1 * 256, ibv + s1 * 256,
        kbw, vbw, vbw, nullptr, nullptr, 2, 4);
    // ---- mab1 fused: q-proj + attention + LN0 + Wo + LN1, xb in-place ----
    mab1_fused<<<dim3(32, 32), 512, 0, stream>>>(
        xb, wq1, ibq + s1 * 256, kbw, vbw, wo1, ibo + s1 * 256,
        ig0 + s1 * 256, ib0 + s1 * 256, ig1 + s1 * 256, ib1 + s1 * 256, xb);
  }
  // ---- PMA: fused K/V projection + attention ----
  attn_fused<2><<<dim3(32, 8), 512, 0, stream>>>(
      q_all + 49152, xb, wt + (size_t)25 * 65536, pbk, wt + (size_t)26 * 65536, pbv, pmask, ob);
  ln4<<<256, 256, 0, stream>>>(ob, ob, pg0, pb0);
  gemm_bp<3, true, 256><<<8, 512, 0, stream>>>(
      ob, wt + (size_t)27 * 65536, wt + (size_t)27 * 65536, wt + (size_t)27 * 65536,
      pbo, pbo, pbo, d_out, d_out, d_out, pg1, pb1, 1, 1);
}